// Round 9
// baseline (191.523 us; speedup 1.0000x reference)
//
#include <hip/hip_runtime.h>
#include <hip/hip_bf16.h>
#include <math.h>

#define BN 8
#define AN 15
#define HH 100
#define WW 168
#define HW (HH*WW)           // 16800
#define NPI (AN*HW)          // 252000 scores per image
#define PRE 2000
#define POST 1000
#define CAP 16384            // candidate buffer per image (12-bit boundary bucket ~8k)
#define ROWW 32              // u64 words per NMS mask row
#define NCHUNK 32            // ceil(PRE/64)
#define RSTRIDE 2048         // padded per-image row stride
#define EPB 4096             // elements per hist block
#define HBLK 62              // ceil(NPI/EPB)
#define GELEM 2048           // elements per gather block
#define GBLK 124             // ceil(NPI/GELEM)

typedef unsigned int u32;
typedef unsigned short u16;
typedef unsigned long long u64;

// ---- workspace layout (bytes) ----
#define OFF_H12    0           // 8*62*4096*2 = 4,063,232 (u16 per-block rows)
#define OFF_THR12  4194304     // 1 KB (thr12 per image, stride 32 u32)
#define OFF_CCNT   4195328     // 1 KB (zeroed by scan12)
#define OFF_CAND   4196352     // 16384*8*8 = 1,048,576
#define OFF_BOX    5244928     // 262144
#define OFF_SCORE  5507072     // 65536
#define OFF_VALID  5572608     // 65536
#define OFF_MASK   5638144     // 4194304
#define OFF_DIAG   9832448     // 131072 -> ~10 MB total

__device__ __forceinline__ u32 fmono(float s) {
  u32 u = __float_as_uint(s);
  return (u & 0x80000000u) ? ~u : (u | 0x80000000u);
}
__device__ __forceinline__ float funmono(u32 m) {
  u32 u = (m & 0x80000000u) ? (m ^ 0x80000000u) : ~m;
  return __uint_as_float(u);
}
__device__ __forceinline__ float areaf(float4 bx) {
  return __fmul_rn(__fadd_rn(__fsub_rn(bx.z, bx.x), 1.0f),
                   __fadd_rn(__fsub_rn(bx.w, bx.y), 1.0f));
}

// raw barrier: LDS ordering only (lgkmcnt), does NOT drain vmcnt
#define BAR_LGKM() asm volatile("s_waitcnt lgkmcnt(0)\ns_barrier" ::: "memory")

// inclusive suffix sum across a 64-lane wave
__device__ __forceinline__ u32 wave_suffix_incl(u32 v, int lane) {
  for (int d = 1; d < 64; d <<= 1) {
    u32 n = (u32)__shfl_down((int)v, d, 64);
    if (lane + d < 64) v += n;
  }
  return v;
}

__device__ __forceinline__ u64 shfl_xor64(u64 v, int m) {
  return (u64)__shfl_xor((unsigned long long)v, m, 64);
}

// ============ hist12: single-pass 12-bit histogram (R21) ==================
// R21: 8->16-bit two-level needed 3 data passes (hist1/hist2/gather). One
// 12-bit level needs 2. 4096 buckets x 4 bank-spread LDS copies (stride
// 4100 -> copy banks 0/4/8/12); hot exp-126 bucket spreads over 16
// sub-buckets -> ~no same-address atomic serialization (hist1's main cost).
// Per-block u16 rows (no atomics -> no zeroing -> no grid-sync needed).
__global__ __launch_bounds__(256) void hist12_kernel(const float* __restrict__ cls,
                                                     u16* __restrict__ h12) {
  __shared__ u32 lh[4 * 4100];   // 65.6 KB
  int b = blockIdx.y;
  int t = threadIdx.x;
  for (int q = t; q < 4 * 4100; q += 256) lh[q] = 0u;
  __syncthreads();
  int start = blockIdx.x * EPB;
  const float* p = cls + (size_t)b * NPI;
  u32 copy = ((u32)t & 3u) * 4100u;
  if (start + EPB <= NPI) {
    const float4* p4 = (const float4*)(p + start);
#pragma unroll
    for (int q = 0; q < 4; ++q) {
      float4 v = p4[q * 256 + t];
      atomicAdd(&lh[copy + (fmono(v.x) >> 20)], 1u);
      atomicAdd(&lh[copy + (fmono(v.y) >> 20)], 1u);
      atomicAdd(&lh[copy + (fmono(v.z) >> 20)], 1u);
      atomicAdd(&lh[copy + (fmono(v.w) >> 20)], 1u);
    }
  } else {
    for (int i = start + t; i < NPI; i += 256) {
      u32 m = fmono(p[i]);
      atomicAdd(&lh[copy + (m >> 20)], 1u);
    }
  }
  __syncthreads();
  u16* row = h12 + ((size_t)(b * HBLK) + blockIdx.x) * 4096;
#pragma unroll
  for (int g = 0; g < 16; ++g) {
    int c = t + 256 * g;
    u32 s = lh[c] + lh[4100 + c] + lh[8200 + c] + lh[12300 + c];
    row[c] = (u16)s;   // max 4096/block < 65536
  }
}

// ============ scan12: column-sum + 4096 suffix scan -> t12 ================
// 8 blocks (one/image), 256 threads. Coalesced u16 row reads; two-level
// suffix scan (16 contiguous buckets/thread + one-wave scan of 256 totals).
// Also zeroes ccnt (replaces hist2's re-arm role).
__global__ __launch_bounds__(256) void scan12_kernel(const u16* __restrict__ h12,
                                                     u32* __restrict__ thr12g,
                                                     u32* __restrict__ ccnt) {
  __shared__ u32 sums[4096];
  __shared__ u32 tot[256];
  __shared__ u32 tails[256];
  int b = blockIdx.x;
  int t = threadIdx.x;
  u32 acc[16];
#pragma unroll
  for (int g = 0; g < 16; ++g) acc[g] = 0u;
  for (int r = 0; r < HBLK; ++r) {
    const u16* row = h12 + ((size_t)(b * HBLK) + r) * 4096;
#pragma unroll
    for (int g = 0; g < 16; ++g) acc[g] += (u32)row[t + 256 * g];
  }
#pragma unroll
  for (int g = 0; g < 16; ++g) sums[t + 256 * g] = acc[g];
  __syncthreads();
  // thread t owns contiguous buckets [16t, 16t+16)
  u32 ls[17];
  ls[16] = 0u;
#pragma unroll
  for (int k = 15; k >= 0; --k) ls[k] = sums[16 * t + k] + ls[k + 1];
  tot[t] = ls[0];
  __syncthreads();
  if (t < 64) {
    u32 a0 = tot[4 * t + 0], a1 = tot[4 * t + 1], a2 = tot[4 * t + 2], a3 = tot[4 * t + 3];
    u32 g3 = a3, g2 = a2 + g3, g1 = a1 + g2, g0 = a0 + g1;
    u32 incl = wave_suffix_incl(g0, t);
    u32 tg = incl - g0;   // suffix after this lane's group of 4 threads
    tails[4 * t + 0] = tg + g1;
    tails[4 * t + 1] = tg + g2;
    tails[4 * t + 2] = tg + g3;
    tails[4 * t + 3] = tg;
  }
  __syncthreads();
  u32 tail = tails[t];
#pragma unroll
  for (int k = 0; k < 16; ++k) {
    u32 Sk = tail + ls[k], Sn = tail + ls[k + 1];
    if (t == 0 && k == 0 && Sk < (u32)PRE) thr12g[b * 32] = 0u;   // total<PRE (never)
    if (Sk >= (u32)PRE && Sn < (u32)PRE) thr12g[b * 32] = (u32)(16 * t + k);
  }
  if (t == 128) ccnt[b * 32] = 0u;
}

// ============ gather v6: one test vs t12 (no per-block scan) ==============
__global__ __launch_bounds__(256) void gather_kernel(
    const float* __restrict__ cls, const u32* __restrict__ thr12g,
    u32* __restrict__ ccnt, u64* __restrict__ cand) {
  __shared__ int wsum[4], wbase[4];
  __shared__ u32 baseSh;
  int b = blockIdx.y;
  int t = threadIdx.x;
  int lane = t & 63, wid = t >> 6;
  u32 T = thr12g[b * 32];
  int base_i = blockIdx.x * GELEM;
  const float* p = cls + (size_t)b * NPI;
  u32 mv[8];
  u32 flags = 0;
  bool vec = (base_i + GELEM <= NPI);
  if (vec) {
    const float4* p4 = (const float4*)(p + base_i);
    float4 a = p4[t], c = p4[256 + t];
#pragma unroll
    for (int k = 0; k < 4; ++k) {
      float vv = (k == 0) ? a.x : (k == 1) ? a.y : (k == 2) ? a.z : a.w;
      u32 m = fmono(vv);
      mv[k] = m;
      flags |= ((m >> 20) >= T) ? (1u << k) : 0u;
    }
#pragma unroll
    for (int k = 0; k < 4; ++k) {
      float vv = (k == 0) ? c.x : (k == 1) ? c.y : (k == 2) ? c.z : c.w;
      u32 m = fmono(vv);
      mv[4 + k] = m;
      flags |= ((m >> 20) >= T) ? (1u << (4 + k)) : 0u;
    }
  } else {
#pragma unroll
    for (int k = 0; k < 8; ++k) {
      int i = base_i + k * 256 + t;
      u32 m = 0;
      bool ok = false;
      if (i < NPI) { m = fmono(p[i]); ok = (m >> 20) >= T; }
      mv[k] = m;
      flags |= ok ? (1u << k) : 0u;
    }
  }
  int ct = (int)__popc(flags);
  int inc = ct;
  for (int d = 1; d < 64; d <<= 1) {
    int n = __shfl_up(inc, d, 64);
    if (lane >= d) inc += n;
  }
  int excl = inc - ct;
  if (lane == 63) wsum[wid] = inc;
  __syncthreads();
  if (t == 0) {
    int acc = 0;
#pragma unroll
    for (int w = 0; w < 4; ++w) { wbase[w] = acc; acc += wsum[w]; }
    baseSh = acc ? atomicAdd(&ccnt[b * 32], (u32)acc) : 0u;
  }
  __syncthreads();
  if (!flags) return;
  u32 pos0 = baseSh + (u32)wbase[wid] + (u32)excl;
#pragma unroll
  for (int k = 0; k < 8; ++k) {
    if ((flags >> k) & 1u) {
      u32 pos = pos0 + (u32)__popc(flags & ((1u << k) - 1u));
      if (pos < CAP) {
        int i = vec ? (base_i + (k < 4 ? 4 * t + k : 1024 + 4 * t + (k - 4)))
                    : (base_i + k * 256 + t);
        int a = i / HW;
        int hw = i - a * HW;
        u32 ti = (u32)(hw * AN + a);   // transposed flat index (h*W + w)*A + a
        cand[(size_t)b * CAP + pos] = ((u64)mv[k] << 32) | (u32)(~ti);
      }
    }
  }
}

// shared transform body: decode one sorted key -> box/score/valid row q
__device__ __forceinline__ void transform_one(
    u64 key, int q, int b, u32 cnt,
    float im_h, float im_w, float wmax, float hmax, float msz,
    const float* __restrict__ bbox, const float* __restrict__ anch,
    float4* __restrict__ boxes, float* __restrict__ scores, int* __restrict__ valid) {
  const float BCLIP = (float)4.135166556742356;  // log(1000/16)
  u32 i = ~((u32)key);
  if (q >= (int)cnt || i >= (u32)NPI) {
    boxes[b * RSTRIDE + q] = make_float4(0.f, 0.f, 0.f, 0.f);
    scores[b * RSTRIDE + q] = 0.f;
    valid[b * RSTRIDE + q] = 0;
    return;
  }
  float sc = funmono((u32)(key >> 32));
  int a = (int)(i % AN);
  int pp = (int)(i / AN);
  int w = pp % WW;
  int h = pp / WW;
  float sx = (float)(w * 8), sy = (float)(h * 8);
  float ax1 = __fadd_rn(anch[a * 4 + 0], sx);
  float ay1 = __fadd_rn(anch[a * 4 + 1], sy);
  float ax2 = __fadd_rn(anch[a * 4 + 2], sx);
  float ay2 = __fadd_rn(anch[a * 4 + 3], sy);
  float wsA = __fadd_rn(__fsub_rn(ax2, ax1), 1.0f);
  float hsA = __fadd_rn(__fsub_rn(ay2, ay1), 1.0f);
  float cx = __fadd_rn(ax1, __fmul_rn(0.5f, wsA));
  float cy = __fadd_rn(ay1, __fmul_rn(0.5f, hsA));
  const float* dp = bbox + ((size_t)b * (4 * AN) + 4 * a) * HW + (size_t)h * WW + w;
  float dx = dp[0], dy = dp[HW], dwv = dp[2 * HW], dhv = dp[3 * HW];
  dwv = fminf(dwv, BCLIP);
  dhv = fminf(dhv, BCLIP);
  float pcx = __fadd_rn(__fmul_rn(dx, wsA), cx);
  float pcy = __fadd_rn(__fmul_rn(dy, hsA), cy);
  float pw = __fmul_rn((float)exp((double)dwv), wsA);
  float ph = __fmul_rn((float)exp((double)dhv), hsA);
  float hpw = __fmul_rn(0.5f, pw), hph = __fmul_rn(0.5f, ph);
  float x1 = __fsub_rn(pcx, hpw);
  float y1 = __fsub_rn(pcy, hph);
  float x2 = __fsub_rn(__fadd_rn(pcx, hpw), 1.0f);
  float y2 = __fsub_rn(__fadd_rn(pcy, hph), 1.0f);
  x1 = fminf(fmaxf(x1, 0.0f), wmax);
  y1 = fminf(fmaxf(y1, 0.0f), hmax);
  x2 = fminf(fmaxf(x2, 0.0f), wmax);
  y2 = fminf(fmaxf(y2, 0.0f), hmax);
  float ws2 = __fadd_rn(__fsub_rn(x2, x1), 1.0f);
  float hs2 = __fadd_rn(__fsub_rn(y2, y1), 1.0f);
  int v = (ws2 >= msz) && (hs2 >= msz) &&
          (__fadd_rn(x1, __fmul_rn(ws2, 0.5f)) < im_w) &&
          (__fadd_rn(y1, __fmul_rn(hs2, 0.5f)) < im_h);
  boxes[b * RSTRIDE + q] = make_float4(x1, y1, x2, y2);
  scores[b * RSTRIDE + q] = sc;
  valid[b * RSTRIDE + q] = v;
}

// ============ sort_transform v6: 12->24-bit refine from global cand =======
// Refine hist (4096 buckets, bits 8..19) built from global cand (~10k keys,
// two coalesced passes) -- no CAP-wide LDS staging. keys2[4096] doubles as
// register-bitonic input (first 2048) and as the tie-fallback LDS sort
// buffer (<=4096 at-threshold keys, same guarantee as before).
__global__ __launch_bounds__(1024) void sort_transform_kernel(
    const u64* __restrict__ cand, const u32* __restrict__ ccnt,
    const u32* __restrict__ thr12g,
    const float* __restrict__ bbox, const float* __restrict__ iminfo,
    const float* __restrict__ anch,
    float4* __restrict__ boxes, float* __restrict__ scores, int* __restrict__ valid) {
  __shared__ u64 keys2[4096];  // 32 KB
  __shared__ u32 h24[4096];    // 16 KB
  __shared__ u32 tot[256];
  __shared__ u32 tails[256];
  __shared__ u32 aboveSh, cmpCnt, t24Sh, cnt2Sh;
  int b = blockIdx.x;
  int t = threadIdx.x;
  int lane = t & 63;
  u32 cnt = ccnt[b * 32];
  if (cnt > CAP) cnt = CAP;
  u32 t12 = thr12g[b * 32];
  keys2[t] = 0ULL; keys2[t + 1024] = 0ULL; keys2[t + 2048] = 0ULL; keys2[t + 3072] = 0ULL;
  for (int q = t; q < 4096; q += 1024) h24[q] = 0u;
  if (t == 0) { aboveSh = 0u; cmpCnt = 0u; }
  __syncthreads();

  // pass A: count strictly-above-t12; refine-hist boundary bucket bits 8..19
  const u64* cb = cand + (size_t)b * CAP;
  for (int q0 = 0; q0 < (int)cnt; q0 += 1024) {
    int q = q0 + t;
    bool isReal = (q < (int)cnt);
    u64 key = isReal ? cb[q] : 0ULL;
    u32 hi = (u32)(key >> 32);
    bool above = isReal && ((hi >> 20) > t12);
    u64 bal = __ballot(above);
    if (lane == 0 && bal) atomicAdd(&aboveSh, (u32)__popcll(bal));
    if (isReal && !above) atomicAdd(&h24[(hi >> 8) & 0xFFFu], 1u);
  }
  __syncthreads();
  // two-level 4096 suffix scan (threads t<256 own 16 contiguous buckets)
  u32 ls[17];
  if (t < 256) {
    ls[16] = 0u;
#pragma unroll
    for (int k = 15; k >= 0; --k) ls[k] = h24[16 * t + k] + ls[k + 1];
    tot[t] = ls[0];
  }
  __syncthreads();
  if (t < 64) {
    u32 a0 = tot[4 * t + 0], a1 = tot[4 * t + 1], a2 = tot[4 * t + 2], a3 = tot[4 * t + 3];
    u32 g3 = a3, g2 = a2 + g3, g1 = a1 + g2, g0 = a0 + g1;
    u32 incl = wave_suffix_incl(g0, t);
    u32 tg = incl - g0;
    tails[4 * t + 0] = tg + g1;
    tails[4 * t + 1] = tg + g2;
    tails[4 * t + 2] = tg + g3;
    tails[4 * t + 3] = tg;
  }
  __syncthreads();
  if (t < 256) {
    u32 basev = aboveSh;
    u32 tail = tails[t];
#pragma unroll
    for (int k = 0; k < 16; ++k) {
      u32 Sk = basev + tail + ls[k], Sn = basev + tail + ls[k + 1];
      if (t == 0 && k == 0 && Sk < (u32)PRE) { t24Sh = 0u; cnt2Sh = Sk; }
      if (Sk >= (u32)PRE && Sn < (u32)PRE) { t24Sh = (u32)(16 * t + k); cnt2Sh = Sk; }
    }
  }
  __syncthreads();
  u32 cnt2 = cnt2Sh;
  u32 t24 = (t12 << 12) | t24Sh;
  bool big = (cnt2 > 2048u);   // block-uniform tie-fallback

  // pass B: compact passing keys into keys2 (capacity 4096, order arbitrary)
  for (int q0 = 0; q0 < (int)cnt; q0 += 1024) {
    int q = q0 + t;
    bool isReal = (q < (int)cnt);
    u64 key = isReal ? cb[q] : 0ULL;
    u32 hi = (u32)(key >> 32);
    bool pass = isReal && ((hi >> 8) >= t24);
    u64 bal = __ballot(pass);
    if (bal) {
      u32 wb = 0;
      if (lane == 0) wb = atomicAdd(&cmpCnt, (u32)__popcll(bal));
      wb = (u32)__shfl((int)wb, 0, 64);
      if (pass) {
        u32 rank = (u32)__popcll(bal & ((1ULL << lane) - 1ULL));
        if (wb + rank < 4096u) keys2[wb + rank] = key;
      }
    }
  }
  __syncthreads();

  float im_h = iminfo[b * 3 + 0], im_w = iminfo[b * 3 + 1], im_s = iminfo[b * 3 + 2];
  float wmax = __fsub_rn(im_w, 1.0f), hmax = __fsub_rn(im_h, 1.0f);
  float msz = __fmul_rn(0.0f, im_s);

  if (!big) {
    // register bitonic over keys2[0..2048): thread t owns V[2t], V[2t+1]
    u64 e0 = keys2[2 * t], e1 = keys2[2 * t + 1];
    for (u32 k = 2; k <= 2048; k <<= 1) {
      u32 kb = k >> 1;
      for (u32 j = k >> 1; j >= 1; j >>= 1) {
        bool up = ((u32)t & kb) == 0;
        if (j >= 128) {
          keys2[2 * t] = e0; keys2[2 * t + 1] = e1;
          __syncthreads();
          int pt = t ^ (int)(j >> 1);
          u64 y0 = keys2[2 * pt], y1 = keys2[2 * pt + 1];
          bool low = ((u32)t & (j >> 1)) == 0;
          bool mx = (up == low);
          e0 = mx ? (e0 > y0 ? e0 : y0) : (e0 < y0 ? e0 : y0);
          e1 = mx ? (e1 > y1 ? e1 : y1) : (e1 < y1 ? e1 : y1);
          __syncthreads();
        } else if (j >= 2) {
          int mm = (int)(j >> 1);
          u64 y0 = shfl_xor64(e0, mm), y1 = shfl_xor64(e1, mm);
          bool low = ((u32)t & (u32)mm) == 0;
          bool mx = (up == low);
          e0 = mx ? (e0 > y0 ? e0 : y0) : (e0 < y0 ? e0 : y0);
          e1 = mx ? (e1 > y1 ? e1 : y1) : (e1 < y1 ? e1 : y1);
        } else {
          u64 mx64 = (e0 > e1) ? e0 : e1;
          u64 mn64 = (e0 > e1) ? e1 : e0;
          e0 = up ? mx64 : mn64;
          e1 = up ? mn64 : mx64;
        }
      }
    }
    if (2 * t < PRE) {
      transform_one(e0, 2 * t, b, cnt, im_h, im_w, wmax, hmax, msz,
                    bbox, anch, boxes, scores, valid);
      transform_one(e1, 2 * t + 1, b, cnt, im_h, im_w, wmax, hmax, msz,
                    bbox, anch, boxes, scores, valid);
    }
  } else {
    // tie-fallback: LDS bitonic over keys2[4096] (zero-padded, descending)
    for (u32 k = 2; k <= 4096; k <<= 1) {
      for (u32 j = k >> 1; j > 0; j >>= 1) {
        for (int p = 0; p < 2; ++p) {
          u32 idx = (u32)t + (u32)p * 1024u;
          u32 base2 = ((idx & ~(j - 1)) << 1) | (idx & (j - 1));
          u32 partner = base2 + j;
          bool up2 = ((base2 & k) == 0);
          u64 A = keys2[base2], Bv = keys2[partner];
          bool sw = up2 ? (A < Bv) : (A > Bv);
          if (sw) { keys2[base2] = Bv; keys2[partner] = A; }
        }
        __syncthreads();
      }
    }
    for (int q = t; q < PRE; q += 1024)
      transform_one(keys2[q], q, b, cnt, im_h, im_w, wmax, hmax, msz,
                    bbox, anch, boxes, scores, valid);
  }
}

// triangular grid: 528 = 32*33/2 blocks per image
__global__ __launch_bounds__(64) void nms_mask_kernel(const float4* __restrict__ boxes,
                                                      u64* __restrict__ mask,
                                                      u64* __restrict__ diag) {
  int L = blockIdx.x, b = blockIdx.y;
  int ib = 0, rowlen = 32;
  while (L >= rowlen) { L -= rowlen; rowlen--; ib++; }
  int jb = ib + L;
  int t = threadIdx.x;
  __shared__ float4 jbox[64];
  __shared__ float jarea[64];
  int jbase = jb * 64;
  int jcount = min(64, PRE - jbase);
  if (t < jcount) {
    float4 bj = boxes[b * RSTRIDE + jbase + t];
    jbox[t] = bj;
    jarea[t] = areaf(bj);
  }
  __syncthreads();
  int i = ib * 64 + t;
  if (i >= PRE) return;
  float4 bi = boxes[b * RSTRIDE + i];
  float ai = areaf(bi);
  u64 word = 0ULL;
  for (int jj = 0; jj < jcount; ++jj) {
    int j = jbase + jj;
    if (j <= i) continue;
    float4 bj = jbox[jj];
    float iw = fmaxf(__fadd_rn(__fsub_rn(fminf(bi.z, bj.z), fmaxf(bi.x, bj.x)), 1.0f), 0.0f);
    float ih = fmaxf(__fadd_rn(__fsub_rn(fminf(bi.w, bj.w), fmaxf(bi.y, bj.y)), 1.0f), 0.0f);
    float inter = __fmul_rn(iw, ih);
    float denom = __fsub_rn(__fadd_rn(ai, jarea[jj]), inter);
    float iou = inter / denom;
    if (iou > 0.7f) word |= (1ULL << jj);
  }
  mask[((size_t)(b * RSTRIDE) + i) * ROWW + jb] = word;
  if (jb == ib) diag[(size_t)b * RSTRIDE + i] = word;   // packed diagonal word
}

// ---------------- seq NMS v13: sparse closure + parallel vbuf prologue ---
__global__ __launch_bounds__(512) void seq_nms_kernel(
    const u64* __restrict__ mask, const u64* __restrict__ diag,
    const int* __restrict__ valid,
    const float4* __restrict__ boxes, const float* __restrict__ scores,
    float* __restrict__ out) {
  int b = blockIdx.x;
  int tid = threadIdx.x;
  int wid = tid >> 6, lane = tid & 63, lw = lane & 31, hf = lane >> 5;
  __shared__ u64 partial[16];
  __shared__ u64 keepbLDS;
  __shared__ u64 vbufLDS[NCHUNK];
  __shared__ u64 kbits_s[NCHUNK];
  __shared__ int chunkoff[NCHUNK];
  __shared__ int keeplist[PRE];
  __shared__ int Ksh;
  __shared__ int stopSh;

  if (tid < 16) partial[tid] = 0ULL;
  if (tid < NCHUNK) kbits_s[tid] = 0ULL;
  if (tid == 0) stopSh = 0;
  // vbuf: all 8 waves in parallel, 4 chunks each
  for (int c = wid * 4; c < wid * 4 + 4; ++c) {
    int q = c * 64 + lane;
    int v = (q < PRE) ? valid[b * RSTRIDE + q] : 0;
    u64 bl = __ballot(v != 0);
    if (lane == 0) vbufLDS[c] = bl;
  }
  __syncthreads();

  const u64* base = mask + (size_t)b * RSTRIDE * ROWW;
  const u64* dg = diag + (size_t)b * RSTRIDE;

  u64 rem = 0ULL;
  u64 Dv = 0ULL;
  if (wid == 0) Dv = dg[lane];   // chunk 0 diag
  int rb0 = wid * 8 + hf;        // this lane's rows: rb0, rb0+2, rb0+4, rb0+6
  int tot = 0;
  u64 cur0 = base[(size_t)(rb0 + 0) * ROWW + lw];
  u64 cur1 = base[(size_t)(rb0 + 2) * ROWW + lw];
  u64 cur2 = base[(size_t)(rb0 + 4) * ROWW + lw];
  u64 cur3 = base[(size_t)(rb0 + 6) * ROWW + lw];
  for (int c = 0; c < NCHUNK; ++c) {
    u64 n0 = 0, n1 = 0, n2 = 0, n3 = 0, Dnext = 0ULL;
    if (c + 1 < NCHUNK) {
      int c0n = (c + 1) * 64;
      n0 = base[(size_t)(c0n + rb0 + 0) * ROWW + lw];
      n1 = base[(size_t)(c0n + rb0 + 2) * ROWW + lw];
      n2 = base[(size_t)(c0n + rb0 + 4) * ROWW + lw];
      n3 = base[(size_t)(c0n + rb0 + 6) * ROWW + lw];
      if (wid == 0) Dnext = dg[(size_t)(c + 1) * 64 + lane];
    }
    if (wid == 0) {
      u64 nz = __ballot(Dv != 0ULL);
      u64 cv = partial[0];
#pragma unroll
      for (int s = 1; s < 16; ++s) cv |= partial[s];
      u32 clo = (u32)__builtin_amdgcn_readfirstlane((int)(u32)cv);
      u32 chi = (u32)__builtin_amdgcn_readfirstlane((int)(u32)(cv >> 32));
      u64 cl = ((u64)chi << 32) | clo;
      u64 vbv = vbufLDS[c];
      u32 vlo = (u32)__builtin_amdgcn_readfirstlane((int)(u32)vbv);
      u32 vhi = (u32)__builtin_amdgcn_readfirstlane((int)(u32)(vbv >> 32));
      u64 vb = ((u64)vhi << 32) | vlo;
      // sparse serial closure (D[ii]==0 iterations are no-ops)
      u32 dloA = (u32)Dv, dhiA = (u32)(Dv >> 32);
      u64 work = nz & vb;
      while (work) {
        int ii = __builtin_ctzll(work);
        work &= work - 1ULL;
        u32 dlo = (u32)__builtin_amdgcn_readlane((int)dloA, ii);
        u32 dhi = (u32)__builtin_amdgcn_readlane((int)dhiA, ii);
        u64 D = ((u64)dhi << 32) | dlo;
        u64 tt = ((~cl & vb) >> ii) & 1ULL;
        cl |= tt ? D : 0ULL;
      }
      u64 keepb = vb & ~cl;
      tot += (int)__popcll(keepb);
      if (lane == 0) {
        keepbLDS = keepb;
        kbits_s[c] = keepb;
        if (tot >= POST) stopSh = 1;
      }
    }
    BAR_LGKM();                           // barrier 1 (vmcnt NOT drained)
    u64 keepb = keepbLDS;
    int stop = stopSh;
    rem |= cur0 & (0ULL - ((keepb >> (rb0 + 0)) & 1ULL));
    rem |= cur1 & (0ULL - ((keepb >> (rb0 + 2)) & 1ULL));
    rem |= cur2 & (0ULL - ((keepb >> (rb0 + 4)) & 1ULL));
    rem |= cur3 & (0ULL - ((keepb >> (rb0 + 6)) & 1ULL));
    int nw = (c + 1) & 31;
    if (lw == nw) partial[wid * 2 + hf] = rem;
    if (stop) break;
    BAR_LGKM();                           // barrier 2
    cur0 = n0; cur1 = n1; cur2 = n2; cur3 = n3;
    Dv = Dnext;
  }
  __syncthreads();

  // compact keep list
  if (wid == 0) {
    int pc = (lane < NCHUNK) ? (int)__popcll(kbits_s[lane]) : 0;
    int inc = pc;
    for (int d = 1; d < 64; d <<= 1) {
      int n = __shfl_up(inc, d, 64);
      if (lane >= d) inc += n;
    }
    if (lane < NCHUNK) chunkoff[lane] = inc - pc;
    if (lane == NCHUNK - 1) Ksh = inc;
  }
  __syncthreads();
  for (int c = wid * 4; c < wid * 4 + 4; ++c) {
    u64 word = kbits_s[c];
    if ((word >> lane) & 1ULL) {
      int rank = (int)__popcll(word & ((1ULL << lane) - 1ULL));
      keeplist[chunkoff[c] + rank] = c * 64 + lane;
    }
  }
  __syncthreads();
  int K = Ksh;

  float* rois = out;
  float* probs = out + (size_t)BN * POST * 5;
  for (int r = tid; r < POST; r += 512) {
    float x1 = 0.f, y1 = 0.f, x2 = 0.f, y2 = 0.f, pr = 0.f;
    if (r < K) {
      int i = keeplist[r];
      float4 bb = boxes[b * RSTRIDE + i];
      x1 = bb.x; y1 = bb.y; x2 = bb.z; y2 = bb.w;
      pr = scores[b * RSTRIDE + i];
    }
    size_t ro = (size_t)(b * POST + r) * 5;
    rois[ro + 0] = (float)b;
    rois[ro + 1] = x1; rois[ro + 2] = y1; rois[ro + 3] = x2; rois[ro + 4] = y2;
    probs[b * POST + r] = pr;
  }
}

extern "C" void kernel_launch(void* const* d_in, const int* in_sizes, int n_in,
                              void* d_out, int out_size, void* d_ws, size_t ws_size,
                              hipStream_t stream) {
  const float* cls    = (const float*)d_in[0];
  const float* bbox   = (const float*)d_in[1];
  const float* iminfo = (const float*)d_in[2];
  const float* anch   = (const float*)d_in[3];
  char* ws = (char*)d_ws;
  u16* h12    = (u16*)(ws + OFF_H12);
  u32* thr12g = (u32*)(ws + OFF_THR12);
  u32* ccnt   = (u32*)(ws + OFF_CCNT);
  u64* cand   = (u64*)(ws + OFF_CAND);
  float4* boxes = (float4*)(ws + OFF_BOX);
  float* scores = (float*)(ws + OFF_SCORE);
  int* valid    = (int*)(ws + OFF_VALID);
  u64* mask     = (u64*)(ws + OFF_MASK);
  u64* diag     = (u64*)(ws + OFF_DIAG);
  float* out = (float*)d_out;

  hist12_kernel<<<dim3(HBLK, BN), 256, 0, stream>>>(cls, h12);
  scan12_kernel<<<BN, 256, 0, stream>>>(h12, thr12g, ccnt);
  gather_kernel<<<dim3(GBLK, BN), 256, 0, stream>>>(cls, thr12g, ccnt, cand);
  sort_transform_kernel<<<BN, 1024, 0, stream>>>(cand, ccnt, thr12g, bbox, iminfo, anch,
                                                 boxes, scores, valid);
  nms_mask_kernel<<<dim3(528, BN), 64, 0, stream>>>(boxes, mask, diag);
  seq_nms_kernel<<<BN, 512, 0, stream>>>(mask, diag, valid, boxes, scores, out);
}

// Round 10
// 162.375 us; speedup vs baseline: 1.1795x; 1.1795x over previous
//
#include <hip/hip_runtime.h>
#include <hip/hip_bf16.h>
#include <math.h>

#define BN 8
#define AN 15
#define HH 100
#define WW 168
#define HW (HH*WW)           // 16800
#define NPI (AN*HW)          // 252000 scores per image
#define PRE 2000
#define POST 1000
#define CAP 4096             // candidate buffer per image
#define ROWW 32              // u64 words per NMS mask row
#define NCHUNK 32            // ceil(PRE/64)
#define RSTRIDE 2048         // padded per-image row stride
#define EPB 4096             // elements per hist block
#define HBLK 62              // ceil(NPI/EPB)
#define GELEM 2048           // elements per gather block
#define GBLK 124             // ceil(NPI/GELEM)

typedef unsigned int u32;
typedef unsigned long long u64;

// ---- workspace layout (bytes) ----
#define OFF_H1     0            // 507904
#define OFF_H2     507904      // 507904 -> 1015808
#define OFF_CSTAR  1015808     // 1024
#define OFF_CCNT   1016832     // 1024 (zeroed by hist2)
#define OFF_THR    1017856     // 1024
#define OFF_CAND   1018880     // 262144
#define OFF_BOX    1281024     // 262144
#define OFF_SCORE  1543168     // 65536
#define OFF_VALID  1608704     // 65536
#define OFF_MASK   1674240     // 4194304
#define OFF_DIAG   5868544     // 131072 -> 5999616
#define OFF_SKEYS  5999616     // 8*2048*8 = 131072 -> ~6.1 MB total

__device__ __forceinline__ u32 fmono(float s) {
  u32 u = __float_as_uint(s);
  return (u & 0x80000000u) ? ~u : (u | 0x80000000u);
}
__device__ __forceinline__ float funmono(u32 m) {
  u32 u = (m & 0x80000000u) ? (m ^ 0x80000000u) : ~m;
  return __uint_as_float(u);
}
__device__ __forceinline__ float areaf(float4 bx) {
  return __fmul_rn(__fadd_rn(__fsub_rn(bx.z, bx.x), 1.0f),
                   __fadd_rn(__fsub_rn(bx.w, bx.y), 1.0f));
}

// raw barrier: LDS ordering only (lgkmcnt), does NOT drain vmcnt
#define BAR_LGKM() asm volatile("s_waitcnt lgkmcnt(0)\ns_barrier" ::: "memory")

// inclusive suffix sum across a 64-lane wave
__device__ __forceinline__ u32 wave_suffix_incl(u32 v, int lane) {
  for (int d = 1; d < 64; d <<= 1) {
    u32 n = (u32)__shfl_down((int)v, d, 64);
    if (lane + d < 64) v += n;
  }
  return v;
}

__device__ __forceinline__ u64 shfl_xor64(u64 v, int m) {
  return (u64)__shfl_xor((unsigned long long)v, m, 64);
}

// phase-1 histogram: 256 coarse buckets (m>>24), LDS-privatized 16-way,
// float4 input. Writes per-block rows unconditionally (no zeroing needed).
__global__ __launch_bounds__(256) void hist1_kernel(const float* __restrict__ cls,
                                                    u32* __restrict__ h1) {
  __shared__ u32 lh[16 * 258];   // 16.5 KB
  int b = blockIdx.y;
  int t = threadIdx.x;
  for (int q = t; q < 16 * 258; q += 256) lh[q] = 0u;
  __syncthreads();
  int start = blockIdx.x * EPB;
  const float* p = cls + (size_t)b * NPI;
  u32 copy = ((u32)t & 15u) * 258u;
  if (start + EPB <= NPI) {
    const float4* p4 = (const float4*)(p + start);
#pragma unroll
    for (int q = 0; q < 4; ++q) {
      float4 v = p4[q * 256 + t];
      atomicAdd(&lh[copy + (fmono(v.x) >> 24)], 1u);
      atomicAdd(&lh[copy + (fmono(v.y) >> 24)], 1u);
      atomicAdd(&lh[copy + (fmono(v.z) >> 24)], 1u);
      atomicAdd(&lh[copy + (fmono(v.w) >> 24)], 1u);
    }
  } else {
    for (int i = start + t; i < NPI; i += 256) {
      u32 m = fmono(p[i]);
      atomicAdd(&lh[copy + (m >> 24)], 1u);
    }
  }
  __syncthreads();
  u32 s = 0;
#pragma unroll
  for (int cpy = 0; cpy < 16; ++cpy) s += lh[cpy * 258 + t];
  h1[((size_t)(b * HBLK) + blockIdx.x) * 256 + t] = s;   // unconditional
}

// phase-2 histogram + fused coarse scan. Each block redundantly sums h1
// rows (L2-resident) and wave-scans for c*; block x==0 publishes cstar and
// zeroes ccnt.
__global__ __launch_bounds__(256) void hist2_kernel(const float* __restrict__ cls,
                                                    const u32* __restrict__ h1,
                                                    u32* __restrict__ cstar,
                                                    u32* __restrict__ ccnt,
                                                    u32* __restrict__ h2) {
  __shared__ u32 cnts[256];
  __shared__ u32 csSh, cbaseSh;
  __shared__ u32 lh[4 * 260];
  int b = blockIdx.y;
  int t = threadIdx.x;
  u32 s = 0;
  for (int blk = 0; blk < HBLK; ++blk) s += h1[((size_t)(b * HBLK) + blk) * 256 + t];
  cnts[t] = s;
  __syncthreads();
  if (t < 64) {
    u32 v0 = cnts[4 * t + 0], v1 = cnts[4 * t + 1];
    u32 v2 = cnts[4 * t + 2], v3 = cnts[4 * t + 3];
    u32 ls3 = v3, ls2 = v2 + ls3, ls1 = v1 + ls2, ls0 = v0 + ls1;
    u32 incl = wave_suffix_incl(ls0, t);
    u32 tail = incl - ls0;
    u32 s0 = tail + ls0, s1 = tail + ls1, s2 = tail + ls2, s3 = tail + ls3;
    u32 e0 = 4 * (u32)t;
    if (t == 0 && s0 < (u32)PRE) { csSh = 0u; cbaseSh = s1; }
    if (s0 >= (u32)PRE && s1 < (u32)PRE) { csSh = e0 + 0; cbaseSh = s1; }
    if (s1 >= (u32)PRE && s2 < (u32)PRE) { csSh = e0 + 1; cbaseSh = s2; }
    if (s2 >= (u32)PRE && s3 < (u32)PRE) { csSh = e0 + 2; cbaseSh = s3; }
    if (s3 >= (u32)PRE && (e0 + 3 == 255u || tail < (u32)PRE)) {
      csSh = e0 + 3;
      cbaseSh = (e0 + 3 == 255u) ? 0u : tail;
    }
  }
  __syncthreads();
  u32 cs = csSh;
  if (blockIdx.x == 0 && t == 64) {
    cstar[b * 32] = cs; cstar[b * 32 + 1] = cbaseSh;
    ccnt[b * 32] = 0u;   // re-arm gather's counter
  }
  // fine hist, 4-way bank-spread copies
  for (int q = t; q < 4 * 260; q += 256) lh[q] = 0u;
  __syncthreads();
  int start = blockIdx.x * EPB;
  const float* p = cls + (size_t)b * NPI;
  u32 copy = ((u32)t & 3u) * 260u;
  if (start + EPB <= NPI) {
    const float4* p4 = (const float4*)(p + start);
#pragma unroll
    for (int q = 0; q < 4; ++q) {
      float4 v = p4[q * 256 + t];
      u32 m;
      m = fmono(v.x); if ((m >> 24) == cs) atomicAdd(&lh[copy + ((m >> 16) & 0xFFu)], 1u);
      m = fmono(v.y); if ((m >> 24) == cs) atomicAdd(&lh[copy + ((m >> 16) & 0xFFu)], 1u);
      m = fmono(v.z); if ((m >> 24) == cs) atomicAdd(&lh[copy + ((m >> 16) & 0xFFu)], 1u);
      m = fmono(v.w); if ((m >> 24) == cs) atomicAdd(&lh[copy + ((m >> 16) & 0xFFu)], 1u);
    }
  } else {
    for (int i = start + t; i < NPI; i += 256) {
      u32 m = fmono(p[i]);
      if ((m >> 24) == cs) atomicAdd(&lh[copy + ((m >> 16) & 0xFFu)], 1u);
    }
  }
  __syncthreads();
  u32 fs = 0;
#pragma unroll
  for (int cpy = 0; cpy < 4; ++cpy) fs += lh[cpy * 260 + t];
  h2[((size_t)(b * HBLK) + blockIdx.x) * 256 + t] = fs;   // unconditional
}

// ---------------- gather: fused fine scan ---------------------------------
__global__ __launch_bounds__(256) void gather_kernel(
    const float* __restrict__ cls, const u32* __restrict__ h2,
    const u32* __restrict__ cstar,
    u32* __restrict__ thr, u32* __restrict__ ccnt, u64* __restrict__ cand) {
  __shared__ u32 cnts[256];
  __shared__ u32 thrSh;
  __shared__ int wsum[4], wbase[4];
  __shared__ u32 baseSh;
  int b = blockIdx.y;
  int t = threadIdx.x;
  int lane = t & 63, wid = t >> 6;
  u32 s = 0;
  for (int blk = 0; blk < HBLK; ++blk) s += h2[((size_t)(b * HBLK) + blk) * 256 + t];
  cnts[t] = s;
  __syncthreads();
  if (t < 64) {
    u32 cs = cstar[b * 32], base = cstar[b * 32 + 1];
    u32 v0 = cnts[4 * t + 0], v1 = cnts[4 * t + 1];
    u32 v2 = cnts[4 * t + 2], v3 = cnts[4 * t + 3];
    u32 ls3 = v3, ls2 = v2 + ls3, ls1 = v1 + ls2, ls0 = v0 + ls1;
    u32 incl = wave_suffix_incl(ls0, t);
    u32 tail = incl - ls0;
    u32 s0 = base + tail + ls0, s1 = base + tail + ls1;
    u32 s2 = base + tail + ls2, s3 = base + tail + ls3;
    u32 sn = base + tail;
    u32 e0 = 4 * (u32)t;
    if (t == 0 && s0 < (u32)PRE) thrSh = (cs << 8);
    if (s0 >= (u32)PRE && s1 < (u32)PRE) thrSh = (cs << 8) | (e0 + 0);
    if (s1 >= (u32)PRE && s2 < (u32)PRE) thrSh = (cs << 8) | (e0 + 1);
    if (s2 >= (u32)PRE && s3 < (u32)PRE) thrSh = (cs << 8) | (e0 + 2);
    if (s3 >= (u32)PRE && (e0 + 3 == 255u || sn < (u32)PRE)) thrSh = (cs << 8) | (e0 + 3);
  }
  __syncthreads();
  u32 T = thrSh;
  if (blockIdx.x == 0 && t == 65) thr[b * 32] = T;   // for sort_kernel

  int base_i = blockIdx.x * GELEM;
  const float* p = cls + (size_t)b * NPI;
  u32 mv[8];
  u32 flags = 0;
  bool vec = (base_i + GELEM <= NPI);
  if (vec) {
    const float4* p4 = (const float4*)(p + base_i);
    float4 a = p4[t], c = p4[256 + t];
#pragma unroll
    for (int k = 0; k < 4; ++k) {
      float vv = (k == 0) ? a.x : (k == 1) ? a.y : (k == 2) ? a.z : a.w;
      u32 m = fmono(vv);
      mv[k] = m;
      flags |= ((m >> 16) >= T) ? (1u << k) : 0u;
    }
#pragma unroll
    for (int k = 0; k < 4; ++k) {
      float vv = (k == 0) ? c.x : (k == 1) ? c.y : (k == 2) ? c.z : c.w;
      u32 m = fmono(vv);
      mv[4 + k] = m;
      flags |= ((m >> 16) >= T) ? (1u << (4 + k)) : 0u;
    }
  } else {
#pragma unroll
    for (int k = 0; k < 8; ++k) {
      int i = base_i + k * 256 + t;
      u32 m = 0;
      bool ok = false;
      if (i < NPI) { m = fmono(p[i]); ok = (m >> 16) >= T; }
      mv[k] = m;
      flags |= ok ? (1u << k) : 0u;
    }
  }
  int ct = (int)__popc(flags);
  int inc = ct;
  for (int d = 1; d < 64; d <<= 1) {
    int n = __shfl_up(inc, d, 64);
    if (lane >= d) inc += n;
  }
  int excl = inc - ct;
  if (lane == 63) wsum[wid] = inc;
  __syncthreads();
  if (t == 0) {
    int acc = 0;
#pragma unroll
    for (int w = 0; w < 4; ++w) { wbase[w] = acc; acc += wsum[w]; }
    baseSh = acc ? atomicAdd(&ccnt[b * 32], (u32)acc) : 0u;
  }
  __syncthreads();
  if (!flags) return;
  u32 pos0 = baseSh + (u32)wbase[wid] + (u32)excl;
#pragma unroll
  for (int k = 0; k < 8; ++k) {
    if ((flags >> k) & 1u) {
      u32 pos = pos0 + (u32)__popc(flags & ((1u << k) - 1u));
      if (pos < CAP) {
        int i = vec ? (base_i + (k < 4 ? 4 * t + k : 1024 + 4 * t + (k - 4)))
                    : (base_i + k * 256 + t);
        int a = i / HW;
        int hw = i - a * HW;
        u32 ti = (u32)(hw * AN + a);   // transposed flat index (h*W + w)*A + a
        cand[(size_t)b * CAP + pos] = ((u64)mv[k] << 32) | (u32)(~ti);
      }
    }
  }
}

// ============ sort v7: refine + compact + bitonic ONLY (R22 split) ========
// R22: R9 counters showed sort_transform's 49us was the TRANSFORM phase's
// scattered bbox gather on 8 CUs (FETCH 4MB, VALUBusy 0.9% -> HBM-latency-
// bound at 8-block parallelism), not the sort. Split: this kernel writes
// sorted top-PRE keys to global skeys; wide transform_kernel decodes them.
__global__ __launch_bounds__(1024) void sort_kernel(
    const u64* __restrict__ cand, const u32* __restrict__ ccnt,
    const u32* __restrict__ thr, u64* __restrict__ skeys) {
  __shared__ u64 keys[CAP];    // 32 KB
  __shared__ u64 keys2[2048];  // 16 KB
  __shared__ u32 h24[256];
  __shared__ u32 aboveSh, cmpCnt, t24Sh, cnt2Sh;
  int b = blockIdx.x;
  int t = threadIdx.x;
  int lane = t & 63;
  u32 cnt = ccnt[b * 32];
  if (cnt > CAP) cnt = CAP;
  u32 thr16v = thr[b * 32];
  for (int q = t; q < CAP; q += 1024) keys[q] = (q < (int)cnt) ? cand[(size_t)b * CAP + q] : 0ULL;
  keys2[t] = 0ULL; keys2[t + 1024] = 0ULL;
  if (t < 256) h24[t] = 0u;
  if (t == 0) { aboveSh = 0u; cmpCnt = 0u; }
  __syncthreads();

  // refine: count strictly-above-thr16, histogram boundary bucket's next 8b
  for (int q0 = 0; q0 < CAP; q0 += 1024) {
    int q = q0 + t;
    u64 key = keys[q];
    u32 hi = (u32)(key >> 32);
    bool isReal = (q < (int)cnt);
    bool above = isReal && ((hi >> 16) > thr16v);
    u64 bal = __ballot(above);
    if (lane == 0 && bal) atomicAdd(&aboveSh, (u32)__popcll(bal));
    if (isReal && !above) atomicAdd(&h24[(hi >> 8) & 0xFFu], 1u);
  }
  __syncthreads();
  // single-wave suffix scan over 256 refine buckets
  if (t < 64) {
    u32 basev = aboveSh;
    u32 v0 = h24[4 * t + 0], v1 = h24[4 * t + 1];
    u32 v2 = h24[4 * t + 2], v3 = h24[4 * t + 3];
    u32 ls3 = v3, ls2 = v2 + ls3, ls1 = v1 + ls2, ls0 = v0 + ls1;
    u32 incl = wave_suffix_incl(ls0, t);
    u32 tail = incl - ls0;
    u32 s0 = basev + tail + ls0, s1 = basev + tail + ls1;
    u32 s2 = basev + tail + ls2, s3 = basev + tail + ls3;
    u32 sn = basev + tail;
    u32 e0 = 4 * (u32)t;
    if (t == 0 && s0 < (u32)PRE) { t24Sh = 0u; cnt2Sh = s0; }
    if (s0 >= (u32)PRE && s1 < (u32)PRE) { t24Sh = e0 + 0; cnt2Sh = s0; }
    if (s1 >= (u32)PRE && s2 < (u32)PRE) { t24Sh = e0 + 1; cnt2Sh = s1; }
    if (s2 >= (u32)PRE && s3 < (u32)PRE) { t24Sh = e0 + 2; cnt2Sh = s2; }
    if (s3 >= (u32)PRE && (e0 + 3 == 255u || sn < (u32)PRE)) { t24Sh = e0 + 3; cnt2Sh = s3; }
  }
  __syncthreads();
  u32 cnt2 = cnt2Sh;
  bool fallback = (cnt2 > 2048u);   // block-uniform

  if (!fallback) {
    u32 t24 = (thr16v << 8) | t24Sh;
    // compact passing keys into keys2 (order arbitrary; sort fixes)
    for (int q0 = 0; q0 < CAP; q0 += 1024) {
      int q = q0 + t;
      u64 key = keys[q];
      u32 hi = (u32)(key >> 32);
      bool pass = (q < (int)cnt) && ((hi >> 8) >= t24);
      u64 bal = __ballot(pass);
      if (bal) {
        u32 wb = 0;
        if (lane == 0) wb = atomicAdd(&cmpCnt, (u32)__popcll(bal));
        wb = (u32)__shfl((int)wb, 0, 64);
        if (pass) {
          u32 rank = (u32)__popcll(bal & ((1ULL << lane) - 1ULL));
          keys2[wb + rank] = key;
        }
      }
    }
    __syncthreads();
    // register bitonic: thread t owns V[2t] (e0), V[2t+1] (e1)
    u64 e0 = keys2[2 * t], e1 = keys2[2 * t + 1];
    for (u32 k = 2; k <= 2048; k <<= 1) {
      u32 kb = k >> 1;
      for (u32 j = k >> 1; j >= 1; j >>= 1) {
        bool up = ((u32)t & kb) == 0;
        if (j >= 128) {
          keys2[2 * t] = e0; keys2[2 * t + 1] = e1;
          __syncthreads();
          int pt = t ^ (int)(j >> 1);
          u64 y0 = keys2[2 * pt], y1 = keys2[2 * pt + 1];
          bool low = ((u32)t & (j >> 1)) == 0;
          bool mx = (up == low);
          e0 = mx ? (e0 > y0 ? e0 : y0) : (e0 < y0 ? e0 : y0);
          e1 = mx ? (e1 > y1 ? e1 : y1) : (e1 < y1 ? e1 : y1);
          __syncthreads();
        } else if (j >= 2) {
          int mm = (int)(j >> 1);
          u64 y0 = shfl_xor64(e0, mm), y1 = shfl_xor64(e1, mm);
          bool low = ((u32)t & (u32)mm) == 0;
          bool mx = (up == low);
          e0 = mx ? (e0 > y0 ? e0 : y0) : (e0 < y0 ? e0 : y0);
          e1 = mx ? (e1 > y1 ? e1 : y1) : (e1 < y1 ? e1 : y1);
        } else {
          u64 mx64 = (e0 > e1) ? e0 : e1;
          u64 mn64 = (e0 > e1) ? e1 : e0;
          e0 = up ? mx64 : mn64;
          e1 = up ? mn64 : mx64;
        }
      }
    }
    if (2 * t < PRE) {
      skeys[(size_t)b * RSTRIDE + 2 * t] = e0;
      skeys[(size_t)b * RSTRIDE + 2 * t + 1] = e1;
    }
  } else {
    // fallback: full 4096 LDS bitonic (rare: >=49 ties in one 24b bucket)
    for (u32 k = 2; k <= CAP; k <<= 1) {
      for (u32 j = k >> 1; j > 0; j >>= 1) {
        for (int p = 0; p < CAP / 2 / 1024; ++p) {
          u32 idx = (u32)t + (u32)p * 1024u;
          u32 base2 = ((idx & ~(j - 1)) << 1) | (idx & (j - 1));
          u32 partner = base2 + j;
          bool up2 = ((base2 & k) == 0);
          u64 A = keys[base2], Bv = keys[partner];
          bool sw = up2 ? (A < Bv) : (A > Bv);
          if (sw) { keys[base2] = Bv; keys[partner] = A; }
        }
        __syncthreads();
      }
    }
    for (int q = t; q < PRE; q += 1024)
      skeys[(size_t)b * RSTRIDE + q] = keys[q];
  }
}

// ============ transform: wide (64 blocks), 1 key/thread (R22) =============
__global__ __launch_bounds__(256) void transform_kernel(
    const u64* __restrict__ skeys, const u32* __restrict__ ccnt,
    const float* __restrict__ bbox, const float* __restrict__ iminfo,
    const float* __restrict__ anch,
    float4* __restrict__ boxes, float* __restrict__ scores, int* __restrict__ valid) {
  const float BCLIP = (float)4.135166556742356;  // log(1000/16)
  int b = blockIdx.y;
  int q = blockIdx.x * 256 + threadIdx.x;
  if (q >= PRE) return;
  u32 cnt = ccnt[b * 32];
  if (cnt > CAP) cnt = CAP;
  u64 key = skeys[(size_t)b * RSTRIDE + q];
  u32 i = ~((u32)key);
  if (q >= (int)cnt || i >= (u32)NPI) {
    boxes[b * RSTRIDE + q] = make_float4(0.f, 0.f, 0.f, 0.f);
    scores[b * RSTRIDE + q] = 0.f;
    valid[b * RSTRIDE + q] = 0;
    return;
  }
  float im_h = iminfo[b * 3 + 0], im_w = iminfo[b * 3 + 1], im_s = iminfo[b * 3 + 2];
  float wmax = __fsub_rn(im_w, 1.0f), hmax = __fsub_rn(im_h, 1.0f);
  float msz = __fmul_rn(0.0f, im_s);
  float sc = funmono((u32)(key >> 32));
  int a = (int)(i % AN);
  int pp = (int)(i / AN);
  int w = pp % WW;
  int h = pp / WW;
  float sx = (float)(w * 8), sy = (float)(h * 8);
  float ax1 = __fadd_rn(anch[a * 4 + 0], sx);
  float ay1 = __fadd_rn(anch[a * 4 + 1], sy);
  float ax2 = __fadd_rn(anch[a * 4 + 2], sx);
  float ay2 = __fadd_rn(anch[a * 4 + 3], sy);
  float wsA = __fadd_rn(__fsub_rn(ax2, ax1), 1.0f);
  float hsA = __fadd_rn(__fsub_rn(ay2, ay1), 1.0f);
  float cx = __fadd_rn(ax1, __fmul_rn(0.5f, wsA));
  float cy = __fadd_rn(ay1, __fmul_rn(0.5f, hsA));
  const float* dp = bbox + ((size_t)b * (4 * AN) + 4 * a) * HW + (size_t)h * WW + w;
  float dx = dp[0], dy = dp[HW], dwv = dp[2 * HW], dhv = dp[3 * HW];
  dwv = fminf(dwv, BCLIP);
  dhv = fminf(dhv, BCLIP);
  float pcx = __fadd_rn(__fmul_rn(dx, wsA), cx);
  float pcy = __fadd_rn(__fmul_rn(dy, hsA), cy);
  float pw = __fmul_rn((float)exp((double)dwv), wsA);
  float ph = __fmul_rn((float)exp((double)dhv), hsA);
  float hpw = __fmul_rn(0.5f, pw), hph = __fmul_rn(0.5f, ph);
  float x1 = __fsub_rn(pcx, hpw);
  float y1 = __fsub_rn(pcy, hph);
  float x2 = __fsub_rn(__fadd_rn(pcx, hpw), 1.0f);
  float y2 = __fsub_rn(__fadd_rn(pcy, hph), 1.0f);
  x1 = fminf(fmaxf(x1, 0.0f), wmax);
  y1 = fminf(fmaxf(y1, 0.0f), hmax);
  x2 = fminf(fmaxf(x2, 0.0f), wmax);
  y2 = fminf(fmaxf(y2, 0.0f), hmax);
  float ws2 = __fadd_rn(__fsub_rn(x2, x1), 1.0f);
  float hs2 = __fadd_rn(__fsub_rn(y2, y1), 1.0f);
  int v = (ws2 >= msz) && (hs2 >= msz) &&
          (__fadd_rn(x1, __fmul_rn(ws2, 0.5f)) < im_w) &&
          (__fadd_rn(y1, __fmul_rn(hs2, 0.5f)) < im_h);
  boxes[b * RSTRIDE + q] = make_float4(x1, y1, x2, y2);
  scores[b * RSTRIDE + q] = sc;
  valid[b * RSTRIDE + q] = v;
}

// triangular grid: 528 = 32*33/2 blocks per image
__global__ __launch_bounds__(64) void nms_mask_kernel(const float4* __restrict__ boxes,
                                                      u64* __restrict__ mask,
                                                      u64* __restrict__ diag) {
  int L = blockIdx.x, b = blockIdx.y;
  int ib = 0, rowlen = 32;
  while (L >= rowlen) { L -= rowlen; rowlen--; ib++; }
  int jb = ib + L;
  int t = threadIdx.x;
  __shared__ float4 jbox[64];
  __shared__ float jarea[64];
  int jbase = jb * 64;
  int jcount = min(64, PRE - jbase);
  if (t < jcount) {
    float4 bj = boxes[b * RSTRIDE + jbase + t];
    jbox[t] = bj;
    jarea[t] = areaf(bj);
  }
  __syncthreads();
  int i = ib * 64 + t;
  if (i >= PRE) return;
  float4 bi = boxes[b * RSTRIDE + i];
  float ai = areaf(bi);
  u64 word = 0ULL;
  for (int jj = 0; jj < jcount; ++jj) {
    int j = jbase + jj;
    if (j <= i) continue;
    float4 bj = jbox[jj];
    float iw = fmaxf(__fadd_rn(__fsub_rn(fminf(bi.z, bj.z), fmaxf(bi.x, bj.x)), 1.0f), 0.0f);
    float ih = fmaxf(__fadd_rn(__fsub_rn(fminf(bi.w, bj.w), fmaxf(bi.y, bj.y)), 1.0f), 0.0f);
    float inter = __fmul_rn(iw, ih);
    float denom = __fsub_rn(__fadd_rn(ai, jarea[jj]), inter);
    float iou = inter / denom;
    if (iou > 0.7f) word |= (1ULL << jj);
  }
  mask[((size_t)(b * RSTRIDE) + i) * ROWW + jb] = word;
  if (jb == ib) diag[(size_t)b * RSTRIDE + i] = word;   // packed diagonal word
}

// ---------------- seq NMS v13: sparse closure + parallel vbuf prologue ---
__global__ __launch_bounds__(512) void seq_nms_kernel(
    const u64* __restrict__ mask, const u64* __restrict__ diag,
    const int* __restrict__ valid,
    const float4* __restrict__ boxes, const float* __restrict__ scores,
    float* __restrict__ out) {
  int b = blockIdx.x;
  int tid = threadIdx.x;
  int wid = tid >> 6, lane = tid & 63, lw = lane & 31, hf = lane >> 5;
  __shared__ u64 partial[16];
  __shared__ u64 keepbLDS;
  __shared__ u64 vbufLDS[NCHUNK];
  __shared__ u64 kbits_s[NCHUNK];
  __shared__ int chunkoff[NCHUNK];
  __shared__ int keeplist[PRE];
  __shared__ int Ksh;
  __shared__ int stopSh;

  if (tid < 16) partial[tid] = 0ULL;
  if (tid < NCHUNK) kbits_s[tid] = 0ULL;
  if (tid == 0) stopSh = 0;
  // vbuf: all 8 waves in parallel, 4 chunks each
  for (int c = wid * 4; c < wid * 4 + 4; ++c) {
    int q = c * 64 + lane;
    int v = (q < PRE) ? valid[b * RSTRIDE + q] : 0;
    u64 bl = __ballot(v != 0);
    if (lane == 0) vbufLDS[c] = bl;
  }
  __syncthreads();

  const u64* base = mask + (size_t)b * RSTRIDE * ROWW;
  const u64* dg = diag + (size_t)b * RSTRIDE;

  u64 rem = 0ULL;
  u64 Dv = 0ULL;
  if (wid == 0) Dv = dg[lane];   // chunk 0 diag
  int rb0 = wid * 8 + hf;        // this lane's rows: rb0, rb0+2, rb0+4, rb0+6
  int tot = 0;
  u64 cur0 = base[(size_t)(rb0 + 0) * ROWW + lw];
  u64 cur1 = base[(size_t)(rb0 + 2) * ROWW + lw];
  u64 cur2 = base[(size_t)(rb0 + 4) * ROWW + lw];
  u64 cur3 = base[(size_t)(rb0 + 6) * ROWW + lw];
  for (int c = 0; c < NCHUNK; ++c) {
    u64 n0 = 0, n1 = 0, n2 = 0, n3 = 0, Dnext = 0ULL;
    if (c + 1 < NCHUNK) {
      int c0n = (c + 1) * 64;
      n0 = base[(size_t)(c0n + rb0 + 0) * ROWW + lw];
      n1 = base[(size_t)(c0n + rb0 + 2) * ROWW + lw];
      n2 = base[(size_t)(c0n + rb0 + 4) * ROWW + lw];
      n3 = base[(size_t)(c0n + rb0 + 6) * ROWW + lw];
      if (wid == 0) Dnext = dg[(size_t)(c + 1) * 64 + lane];
    }
    if (wid == 0) {
      u64 nz = __ballot(Dv != 0ULL);
      u64 cv = partial[0];
#pragma unroll
      for (int s = 1; s < 16; ++s) cv |= partial[s];
      u32 clo = (u32)__builtin_amdgcn_readfirstlane((int)(u32)cv);
      u32 chi = (u32)__builtin_amdgcn_readfirstlane((int)(u32)(cv >> 32));
      u64 cl = ((u64)chi << 32) | clo;
      u64 vbv = vbufLDS[c];
      u32 vlo = (u32)__builtin_amdgcn_readfirstlane((int)(u32)vbv);
      u32 vhi = (u32)__builtin_amdgcn_readfirstlane((int)(u32)(vbv >> 32));
      u64 vb = ((u64)vhi << 32) | vlo;
      // sparse serial closure (D[ii]==0 iterations are no-ops)
      u32 dloA = (u32)Dv, dhiA = (u32)(Dv >> 32);
      u64 work = nz & vb;
      while (work) {
        int ii = __builtin_ctzll(work);
        work &= work - 1ULL;
        u32 dlo = (u32)__builtin_amdgcn_readlane((int)dloA, ii);
        u32 dhi = (u32)__builtin_amdgcn_readlane((int)dhiA, ii);
        u64 D = ((u64)dhi << 32) | dlo;
        u64 tt = ((~cl & vb) >> ii) & 1ULL;
        cl |= tt ? D : 0ULL;
      }
      u64 keepb = vb & ~cl;
      tot += (int)__popcll(keepb);
      if (lane == 0) {
        keepbLDS = keepb;
        kbits_s[c] = keepb;
        if (tot >= POST) stopSh = 1;
      }
    }
    BAR_LGKM();                           // barrier 1 (vmcnt NOT drained)
    u64 keepb = keepbLDS;
    int stop = stopSh;
    rem |= cur0 & (0ULL - ((keepb >> (rb0 + 0)) & 1ULL));
    rem |= cur1 & (0ULL - ((keepb >> (rb0 + 2)) & 1ULL));
    rem |= cur2 & (0ULL - ((keepb >> (rb0 + 4)) & 1ULL));
    rem |= cur3 & (0ULL - ((keepb >> (rb0 + 6)) & 1ULL));
    int nw = (c + 1) & 31;
    if (lw == nw) partial[wid * 2 + hf] = rem;
    if (stop) break;
    BAR_LGKM();                           // barrier 2
    cur0 = n0; cur1 = n1; cur2 = n2; cur3 = n3;
    Dv = Dnext;
  }
  __syncthreads();

  // compact keep list
  if (wid == 0) {
    int pc = (lane < NCHUNK) ? (int)__popcll(kbits_s[lane]) : 0;
    int inc = pc;
    for (int d = 1; d < 64; d <<= 1) {
      int n = __shfl_up(inc, d, 64);
      if (lane >= d) inc += n;
    }
    if (lane < NCHUNK) chunkoff[lane] = inc - pc;
    if (lane == NCHUNK - 1) Ksh = inc;
  }
  __syncthreads();
  for (int c = wid * 4; c < wid * 4 + 4; ++c) {
    u64 word = kbits_s[c];
    if ((word >> lane) & 1ULL) {
      int rank = (int)__popcll(word & ((1ULL << lane) - 1ULL));
      keeplist[chunkoff[c] + rank] = c * 64 + lane;
    }
  }
  __syncthreads();
  int K = Ksh;

  float* rois = out;
  float* probs = out + (size_t)BN * POST * 5;
  for (int r = tid; r < POST; r += 512) {
    float x1 = 0.f, y1 = 0.f, x2 = 0.f, y2 = 0.f, pr = 0.f;
    if (r < K) {
      int i = keeplist[r];
      float4 bb = boxes[b * RSTRIDE + i];
      x1 = bb.x; y1 = bb.y; x2 = bb.z; y2 = bb.w;
      pr = scores[b * RSTRIDE + i];
    }
    size_t ro = (size_t)(b * POST + r) * 5;
    rois[ro + 0] = (float)b;
    rois[ro + 1] = x1; rois[ro + 2] = y1; rois[ro + 3] = x2; rois[ro + 4] = y2;
    probs[b * POST + r] = pr;
  }
}

extern "C" void kernel_launch(void* const* d_in, const int* in_sizes, int n_in,
                              void* d_out, int out_size, void* d_ws, size_t ws_size,
                              hipStream_t stream) {
  const float* cls    = (const float*)d_in[0];
  const float* bbox   = (const float*)d_in[1];
  const float* iminfo = (const float*)d_in[2];
  const float* anch   = (const float*)d_in[3];
  char* ws = (char*)d_ws;
  u32* h1    = (u32*)(ws + OFF_H1);
  u32* h2    = (u32*)(ws + OFF_H2);
  u32* cstar = (u32*)(ws + OFF_CSTAR);
  u32* ccnt  = (u32*)(ws + OFF_CCNT);
  u32* thr   = (u32*)(ws + OFF_THR);
  u64* cand  = (u64*)(ws + OFF_CAND);
  float4* boxes = (float4*)(ws + OFF_BOX);
  float* scores = (float*)(ws + OFF_SCORE);
  int* valid    = (int*)(ws + OFF_VALID);
  u64* mask     = (u64*)(ws + OFF_MASK);
  u64* diag     = (u64*)(ws + OFF_DIAG);
  u64* skeys    = (u64*)(ws + OFF_SKEYS);
  float* out = (float*)d_out;

  hist1_kernel<<<dim3(HBLK, BN), 256, 0, stream>>>(cls, h1);
  hist2_kernel<<<dim3(HBLK, BN), 256, 0, stream>>>(cls, h1, cstar, ccnt, h2);
  gather_kernel<<<dim3(GBLK, BN), 256, 0, stream>>>(cls, h2, cstar, thr, ccnt, cand);
  sort_kernel<<<BN, 1024, 0, stream>>>(cand, ccnt, thr, skeys);
  transform_kernel<<<dim3(8, BN), 256, 0, stream>>>(skeys, ccnt, bbox, iminfo, anch,
                                                    boxes, scores, valid);
  nms_mask_kernel<<<dim3(528, BN), 64, 0, stream>>>(boxes, mask, diag);
  seq_nms_kernel<<<BN, 512, 0, stream>>>(mask, diag, valid, boxes, scores, out);
}

// Round 11
// 162.181 us; speedup vs baseline: 1.1809x; 1.0012x over previous
//
#include <hip/hip_runtime.h>
#include <hip/hip_bf16.h>
#include <math.h>

#define BN 8
#define AN 15
#define HH 100
#define WW 168
#define HW (HH*WW)           // 16800
#define NPI (AN*HW)          // 252000 scores per image
#define PRE 2000
#define POST 1000
#define CAP 4096             // candidate buffer per image
#define ROWW 32              // u64 words per NMS mask row
#define NCHUNK 32            // ceil(PRE/64)
#define RSTRIDE 2048         // padded per-image row stride
#define EPB 4096             // elements per hist block
#define HBLK 62              // ceil(NPI/EPB)
#define GELEM 2048           // elements per gather block
#define GBLK 124             // ceil(NPI/GELEM)

typedef unsigned int u32;
typedef unsigned long long u64;

// ---- workspace layout (bytes) ----
#define OFF_H1     0            // 507904
#define OFF_H2     507904      // 507904 -> 1015808
#define OFF_CSTAR  1015808     // 1024
#define OFF_CCNT   1016832     // 1024 (zeroed by hist2)
#define OFF_THR    1017856     // 1024
#define OFF_CAND   1018880     // 262144
#define OFF_BOX    1281024     // 262144
#define OFF_SCORE  1543168     // 65536
#define OFF_VALID  1608704     // 65536
#define OFF_MASK   1674240     // 4194304
#define OFF_DIAG   5868544     // 131072 -> 5999616
#define OFF_SKEYS  5999616     // 8*2048*8 = 131072 -> ~6.1 MB total

__device__ __forceinline__ u32 fmono(float s) {
  u32 u = __float_as_uint(s);
  return (u & 0x80000000u) ? ~u : (u | 0x80000000u);
}
__device__ __forceinline__ float funmono(u32 m) {
  u32 u = (m & 0x80000000u) ? (m ^ 0x80000000u) : ~m;
  return __uint_as_float(u);
}
__device__ __forceinline__ float areaf(float4 bx) {
  return __fmul_rn(__fadd_rn(__fsub_rn(bx.z, bx.x), 1.0f),
                   __fadd_rn(__fsub_rn(bx.w, bx.y), 1.0f));
}

// raw barrier: LDS ordering only (lgkmcnt), does NOT drain vmcnt
#define BAR_LGKM() asm volatile("s_waitcnt lgkmcnt(0)\ns_barrier" ::: "memory")

// inclusive suffix sum across a 64-lane wave
__device__ __forceinline__ u32 wave_suffix_incl(u32 v, int lane) {
  for (int d = 1; d < 64; d <<= 1) {
    u32 n = (u32)__shfl_down((int)v, d, 64);
    if (lane + d < 64) v += n;
  }
  return v;
}

__device__ __forceinline__ u64 shfl_xor64(u64 v, int m) {
  return (u64)__shfl_xor((unsigned long long)v, m, 64);
}

// phase-1 histogram: 256 coarse buckets (m>>24), LDS-privatized 16-way,
// float4 input. Writes per-block rows unconditionally (no zeroing needed).
__global__ __launch_bounds__(256) void hist1_kernel(const float* __restrict__ cls,
                                                    u32* __restrict__ h1) {
  __shared__ u32 lh[16 * 258];   // 16.5 KB
  int b = blockIdx.y;
  int t = threadIdx.x;
  for (int q = t; q < 16 * 258; q += 256) lh[q] = 0u;
  __syncthreads();
  int start = blockIdx.x * EPB;
  const float* p = cls + (size_t)b * NPI;
  u32 copy = ((u32)t & 15u) * 258u;
  if (start + EPB <= NPI) {
    const float4* p4 = (const float4*)(p + start);
#pragma unroll
    for (int q = 0; q < 4; ++q) {
      float4 v = p4[q * 256 + t];
      atomicAdd(&lh[copy + (fmono(v.x) >> 24)], 1u);
      atomicAdd(&lh[copy + (fmono(v.y) >> 24)], 1u);
      atomicAdd(&lh[copy + (fmono(v.z) >> 24)], 1u);
      atomicAdd(&lh[copy + (fmono(v.w) >> 24)], 1u);
    }
  } else {
    for (int i = start + t; i < NPI; i += 256) {
      u32 m = fmono(p[i]);
      atomicAdd(&lh[copy + (m >> 24)], 1u);
    }
  }
  __syncthreads();
  u32 s = 0;
#pragma unroll
  for (int cpy = 0; cpy < 16; ++cpy) s += lh[cpy * 258 + t];
  h1[((size_t)(b * HBLK) + blockIdx.x) * 256 + t] = s;   // unconditional
}

// phase-2 histogram + fused coarse scan. Each block redundantly sums h1
// rows (L2-resident) and wave-scans for c*; block x==0 publishes cstar and
// zeroes ccnt.
__global__ __launch_bounds__(256) void hist2_kernel(const float* __restrict__ cls,
                                                    const u32* __restrict__ h1,
                                                    u32* __restrict__ cstar,
                                                    u32* __restrict__ ccnt,
                                                    u32* __restrict__ h2) {
  __shared__ u32 cnts[256];
  __shared__ u32 csSh, cbaseSh;
  __shared__ u32 lh[4 * 260];
  int b = blockIdx.y;
  int t = threadIdx.x;
  u32 s = 0;
  for (int blk = 0; blk < HBLK; ++blk) s += h1[((size_t)(b * HBLK) + blk) * 256 + t];
  cnts[t] = s;
  __syncthreads();
  if (t < 64) {
    u32 v0 = cnts[4 * t + 0], v1 = cnts[4 * t + 1];
    u32 v2 = cnts[4 * t + 2], v3 = cnts[4 * t + 3];
    u32 ls3 = v3, ls2 = v2 + ls3, ls1 = v1 + ls2, ls0 = v0 + ls1;
    u32 incl = wave_suffix_incl(ls0, t);
    u32 tail = incl - ls0;
    u32 s0 = tail + ls0, s1 = tail + ls1, s2 = tail + ls2, s3 = tail + ls3;
    u32 e0 = 4 * (u32)t;
    if (t == 0 && s0 < (u32)PRE) { csSh = 0u; cbaseSh = s1; }
    if (s0 >= (u32)PRE && s1 < (u32)PRE) { csSh = e0 + 0; cbaseSh = s1; }
    if (s1 >= (u32)PRE && s2 < (u32)PRE) { csSh = e0 + 1; cbaseSh = s2; }
    if (s2 >= (u32)PRE && s3 < (u32)PRE) { csSh = e0 + 2; cbaseSh = s3; }
    if (s3 >= (u32)PRE && (e0 + 3 == 255u || tail < (u32)PRE)) {
      csSh = e0 + 3;
      cbaseSh = (e0 + 3 == 255u) ? 0u : tail;
    }
  }
  __syncthreads();
  u32 cs = csSh;
  if (blockIdx.x == 0 && t == 64) {
    cstar[b * 32] = cs; cstar[b * 32 + 1] = cbaseSh;
    ccnt[b * 32] = 0u;   // re-arm gather's counter
  }
  // fine hist, 4-way bank-spread copies
  for (int q = t; q < 4 * 260; q += 256) lh[q] = 0u;
  __syncthreads();
  int start = blockIdx.x * EPB;
  const float* p = cls + (size_t)b * NPI;
  u32 copy = ((u32)t & 3u) * 260u;
  if (start + EPB <= NPI) {
    const float4* p4 = (const float4*)(p + start);
#pragma unroll
    for (int q = 0; q < 4; ++q) {
      float4 v = p4[q * 256 + t];
      u32 m;
      m = fmono(v.x); if ((m >> 24) == cs) atomicAdd(&lh[copy + ((m >> 16) & 0xFFu)], 1u);
      m = fmono(v.y); if ((m >> 24) == cs) atomicAdd(&lh[copy + ((m >> 16) & 0xFFu)], 1u);
      m = fmono(v.z); if ((m >> 24) == cs) atomicAdd(&lh[copy + ((m >> 16) & 0xFFu)], 1u);
      m = fmono(v.w); if ((m >> 24) == cs) atomicAdd(&lh[copy + ((m >> 16) & 0xFFu)], 1u);
    }
  } else {
    for (int i = start + t; i < NPI; i += 256) {
      u32 m = fmono(p[i]);
      if ((m >> 24) == cs) atomicAdd(&lh[copy + ((m >> 16) & 0xFFu)], 1u);
    }
  }
  __syncthreads();
  u32 fs = 0;
#pragma unroll
  for (int cpy = 0; cpy < 4; ++cpy) fs += lh[cpy * 260 + t];
  h2[((size_t)(b * HBLK) + blockIdx.x) * 256 + t] = fs;   // unconditional
}

// ---------------- gather: fused fine scan ---------------------------------
__global__ __launch_bounds__(256) void gather_kernel(
    const float* __restrict__ cls, const u32* __restrict__ h2,
    const u32* __restrict__ cstar,
    u32* __restrict__ thr, u32* __restrict__ ccnt, u64* __restrict__ cand) {
  __shared__ u32 cnts[256];
  __shared__ u32 thrSh;
  __shared__ int wsum[4], wbase[4];
  __shared__ u32 baseSh;
  int b = blockIdx.y;
  int t = threadIdx.x;
  int lane = t & 63, wid = t >> 6;
  u32 s = 0;
  for (int blk = 0; blk < HBLK; ++blk) s += h2[((size_t)(b * HBLK) + blk) * 256 + t];
  cnts[t] = s;
  __syncthreads();
  if (t < 64) {
    u32 cs = cstar[b * 32], base = cstar[b * 32 + 1];
    u32 v0 = cnts[4 * t + 0], v1 = cnts[4 * t + 1];
    u32 v2 = cnts[4 * t + 2], v3 = cnts[4 * t + 3];
    u32 ls3 = v3, ls2 = v2 + ls3, ls1 = v1 + ls2, ls0 = v0 + ls1;
    u32 incl = wave_suffix_incl(ls0, t);
    u32 tail = incl - ls0;
    u32 s0 = base + tail + ls0, s1 = base + tail + ls1;
    u32 s2 = base + tail + ls2, s3 = base + tail + ls3;
    u32 sn = base + tail;
    u32 e0 = 4 * (u32)t;
    if (t == 0 && s0 < (u32)PRE) thrSh = (cs << 8);
    if (s0 >= (u32)PRE && s1 < (u32)PRE) thrSh = (cs << 8) | (e0 + 0);
    if (s1 >= (u32)PRE && s2 < (u32)PRE) thrSh = (cs << 8) | (e0 + 1);
    if (s2 >= (u32)PRE && s3 < (u32)PRE) thrSh = (cs << 8) | (e0 + 2);
    if (s3 >= (u32)PRE && (e0 + 3 == 255u || sn < (u32)PRE)) thrSh = (cs << 8) | (e0 + 3);
  }
  __syncthreads();
  u32 T = thrSh;
  if (blockIdx.x == 0 && t == 65) thr[b * 32] = T;   // for sort_kernel

  int base_i = blockIdx.x * GELEM;
  const float* p = cls + (size_t)b * NPI;
  u32 mv[8];
  u32 flags = 0;
  bool vec = (base_i + GELEM <= NPI);
  if (vec) {
    const float4* p4 = (const float4*)(p + base_i);
    float4 a = p4[t], c = p4[256 + t];
#pragma unroll
    for (int k = 0; k < 4; ++k) {
      float vv = (k == 0) ? a.x : (k == 1) ? a.y : (k == 2) ? a.z : a.w;
      u32 m = fmono(vv);
      mv[k] = m;
      flags |= ((m >> 16) >= T) ? (1u << k) : 0u;
    }
#pragma unroll
    for (int k = 0; k < 4; ++k) {
      float vv = (k == 0) ? c.x : (k == 1) ? c.y : (k == 2) ? c.z : c.w;
      u32 m = fmono(vv);
      mv[4 + k] = m;
      flags |= ((m >> 16) >= T) ? (1u << (4 + k)) : 0u;
    }
  } else {
#pragma unroll
    for (int k = 0; k < 8; ++k) {
      int i = base_i + k * 256 + t;
      u32 m = 0;
      bool ok = false;
      if (i < NPI) { m = fmono(p[i]); ok = (m >> 16) >= T; }
      mv[k] = m;
      flags |= ok ? (1u << k) : 0u;
    }
  }
  int ct = (int)__popc(flags);
  int inc = ct;
  for (int d = 1; d < 64; d <<= 1) {
    int n = __shfl_up(inc, d, 64);
    if (lane >= d) inc += n;
  }
  int excl = inc - ct;
  if (lane == 63) wsum[wid] = inc;
  __syncthreads();
  if (t == 0) {
    int acc = 0;
#pragma unroll
    for (int w = 0; w < 4; ++w) { wbase[w] = acc; acc += wsum[w]; }
    baseSh = acc ? atomicAdd(&ccnt[b * 32], (u32)acc) : 0u;
  }
  __syncthreads();
  if (!flags) return;
  u32 pos0 = baseSh + (u32)wbase[wid] + (u32)excl;
#pragma unroll
  for (int k = 0; k < 8; ++k) {
    if ((flags >> k) & 1u) {
      u32 pos = pos0 + (u32)__popc(flags & ((1u << k) - 1u));
      if (pos < CAP) {
        int i = vec ? (base_i + (k < 4 ? 4 * t + k : 1024 + 4 * t + (k - 4)))
                    : (base_i + k * 256 + t);
        int a = i / HW;
        int hw = i - a * HW;
        u32 ti = (u32)(hw * AN + a);   // transposed flat index (h*W + w)*A + a
        cand[(size_t)b * CAP + pos] = ((u64)mv[k] << 32) | (u32)(~ti);
      }
    }
  }
}

// ============ sort v8: global refine/compact, LDS staging only in fallback
// R23: common path never needed the CAP-wide LDS staging -- refine and
// compact are two streaming passes over ~25 KB of L2-hot cand. Stage into
// LDS only for the (practically never) tie-fallback full bitonic.
__global__ __launch_bounds__(1024) void sort_kernel(
    const u64* __restrict__ cand, const u32* __restrict__ ccnt,
    const u32* __restrict__ thr, u64* __restrict__ skeys) {
  __shared__ u64 keys[CAP];    // 32 KB (fallback only)
  __shared__ u64 keys2[2048];  // 16 KB
  __shared__ u32 h24[256];
  __shared__ u32 aboveSh, cmpCnt, t24Sh, cnt2Sh;
  int b = blockIdx.x;
  int t = threadIdx.x;
  int lane = t & 63;
  u32 cnt = ccnt[b * 32];
  if (cnt > CAP) cnt = CAP;
  u32 thr16v = thr[b * 32];
  const u64* cb = cand + (size_t)b * CAP;
  keys2[t] = 0ULL; keys2[t + 1024] = 0ULL;
  if (t < 256) h24[t] = 0u;
  if (t == 0) { aboveSh = 0u; cmpCnt = 0u; }
  __syncthreads();

  // refine (from global, L2-hot): count strictly-above-thr16, histogram
  // boundary bucket's next 8 bits
  for (int q0 = 0; q0 < CAP; q0 += 1024) {
    int q = q0 + t;
    bool isReal = (q < (int)cnt);
    u64 key = isReal ? cb[q] : 0ULL;
    u32 hi = (u32)(key >> 32);
    bool above = isReal && ((hi >> 16) > thr16v);
    u64 bal = __ballot(above);
    if (lane == 0 && bal) atomicAdd(&aboveSh, (u32)__popcll(bal));
    if (isReal && !above) atomicAdd(&h24[(hi >> 8) & 0xFFu], 1u);
  }
  __syncthreads();
  // single-wave suffix scan over 256 refine buckets
  if (t < 64) {
    u32 basev = aboveSh;
    u32 v0 = h24[4 * t + 0], v1 = h24[4 * t + 1];
    u32 v2 = h24[4 * t + 2], v3 = h24[4 * t + 3];
    u32 ls3 = v3, ls2 = v2 + ls3, ls1 = v1 + ls2, ls0 = v0 + ls1;
    u32 incl = wave_suffix_incl(ls0, t);
    u32 tail = incl - ls0;
    u32 s0 = basev + tail + ls0, s1 = basev + tail + ls1;
    u32 s2 = basev + tail + ls2, s3 = basev + tail + ls3;
    u32 sn = basev + tail;
    u32 e0 = 4 * (u32)t;
    if (t == 0 && s0 < (u32)PRE) { t24Sh = 0u; cnt2Sh = s0; }
    if (s0 >= (u32)PRE && s1 < (u32)PRE) { t24Sh = e0 + 0; cnt2Sh = s0; }
    if (s1 >= (u32)PRE && s2 < (u32)PRE) { t24Sh = e0 + 1; cnt2Sh = s1; }
    if (s2 >= (u32)PRE && s3 < (u32)PRE) { t24Sh = e0 + 2; cnt2Sh = s2; }
    if (s3 >= (u32)PRE && (e0 + 3 == 255u || sn < (u32)PRE)) { t24Sh = e0 + 3; cnt2Sh = s3; }
  }
  __syncthreads();
  u32 cnt2 = cnt2Sh;
  bool fallback = (cnt2 > 2048u);   // block-uniform

  if (!fallback) {
    u32 t24 = (thr16v << 8) | t24Sh;
    // compact passing keys into keys2 (from global; order arbitrary)
    for (int q0 = 0; q0 < CAP; q0 += 1024) {
      int q = q0 + t;
      bool isReal = (q < (int)cnt);
      u64 key = isReal ? cb[q] : 0ULL;
      u32 hi = (u32)(key >> 32);
      bool pass = isReal && ((hi >> 8) >= t24);
      u64 bal = __ballot(pass);
      if (bal) {
        u32 wb = 0;
        if (lane == 0) wb = atomicAdd(&cmpCnt, (u32)__popcll(bal));
        wb = (u32)__shfl((int)wb, 0, 64);
        if (pass) {
          u32 rank = (u32)__popcll(bal & ((1ULL << lane) - 1ULL));
          keys2[wb + rank] = key;
        }
      }
    }
    __syncthreads();
    // register bitonic: thread t owns V[2t] (e0), V[2t+1] (e1)
    u64 e0 = keys2[2 * t], e1 = keys2[2 * t + 1];
    for (u32 k = 2; k <= 2048; k <<= 1) {
      u32 kb = k >> 1;
      for (u32 j = k >> 1; j >= 1; j >>= 1) {
        bool up = ((u32)t & kb) == 0;
        if (j >= 128) {
          keys2[2 * t] = e0; keys2[2 * t + 1] = e1;
          __syncthreads();
          int pt = t ^ (int)(j >> 1);
          u64 y0 = keys2[2 * pt], y1 = keys2[2 * pt + 1];
          bool low = ((u32)t & (j >> 1)) == 0;
          bool mx = (up == low);
          e0 = mx ? (e0 > y0 ? e0 : y0) : (e0 < y0 ? e0 : y0);
          e1 = mx ? (e1 > y1 ? e1 : y1) : (e1 < y1 ? e1 : y1);
          __syncthreads();
        } else if (j >= 2) {
          int mm = (int)(j >> 1);
          u64 y0 = shfl_xor64(e0, mm), y1 = shfl_xor64(e1, mm);
          bool low = ((u32)t & (u32)mm) == 0;
          bool mx = (up == low);
          e0 = mx ? (e0 > y0 ? e0 : y0) : (e0 < y0 ? e0 : y0);
          e1 = mx ? (e1 > y1 ? e1 : y1) : (e1 < y1 ? e1 : y1);
        } else {
          u64 mx64 = (e0 > e1) ? e0 : e1;
          u64 mn64 = (e0 > e1) ? e1 : e0;
          e0 = up ? mx64 : mn64;
          e1 = up ? mn64 : mx64;
        }
      }
    }
    if (2 * t < PRE) {
      skeys[(size_t)b * RSTRIDE + 2 * t] = e0;
      skeys[(size_t)b * RSTRIDE + 2 * t + 1] = e1;
    }
  } else {
    // tie-fallback (rare: >=49 equal 24-bit scores): stage then LDS bitonic
    for (int q = t; q < CAP; q += 1024) keys[q] = (q < (int)cnt) ? cb[q] : 0ULL;
    __syncthreads();
    for (u32 k = 2; k <= CAP; k <<= 1) {
      for (u32 j = k >> 1; j > 0; j >>= 1) {
        for (int p = 0; p < CAP / 2 / 1024; ++p) {
          u32 idx = (u32)t + (u32)p * 1024u;
          u32 base2 = ((idx & ~(j - 1)) << 1) | (idx & (j - 1));
          u32 partner = base2 + j;
          bool up2 = ((base2 & k) == 0);
          u64 A = keys[base2], Bv = keys[partner];
          bool sw = up2 ? (A < Bv) : (A > Bv);
          if (sw) { keys[base2] = Bv; keys[partner] = A; }
        }
        __syncthreads();
      }
    }
    for (int q = t; q < PRE; q += 1024)
      skeys[(size_t)b * RSTRIDE + q] = keys[q];
  }
}

// ============ transform: wide (64 blocks), 1 key/thread ===================
__global__ __launch_bounds__(256) void transform_kernel(
    const u64* __restrict__ skeys, const u32* __restrict__ ccnt,
    const float* __restrict__ bbox, const float* __restrict__ iminfo,
    const float* __restrict__ anch,
    float4* __restrict__ boxes, float* __restrict__ scores, int* __restrict__ valid) {
  const float BCLIP = (float)4.135166556742356;  // log(1000/16)
  int b = blockIdx.y;
  int q = blockIdx.x * 256 + threadIdx.x;
  if (q >= PRE) return;
  u32 cnt = ccnt[b * 32];
  if (cnt > CAP) cnt = CAP;
  u64 key = skeys[(size_t)b * RSTRIDE + q];
  u32 i = ~((u32)key);
  if (q >= (int)cnt || i >= (u32)NPI) {
    boxes[b * RSTRIDE + q] = make_float4(0.f, 0.f, 0.f, 0.f);
    scores[b * RSTRIDE + q] = 0.f;
    valid[b * RSTRIDE + q] = 0;
    return;
  }
  float im_h = iminfo[b * 3 + 0], im_w = iminfo[b * 3 + 1], im_s = iminfo[b * 3 + 2];
  float wmax = __fsub_rn(im_w, 1.0f), hmax = __fsub_rn(im_h, 1.0f);
  float msz = __fmul_rn(0.0f, im_s);
  float sc = funmono((u32)(key >> 32));
  int a = (int)(i % AN);
  int pp = (int)(i / AN);
  int w = pp % WW;
  int h = pp / WW;
  float sx = (float)(w * 8), sy = (float)(h * 8);
  float ax1 = __fadd_rn(anch[a * 4 + 0], sx);
  float ay1 = __fadd_rn(anch[a * 4 + 1], sy);
  float ax2 = __fadd_rn(anch[a * 4 + 2], sx);
  float ay2 = __fadd_rn(anch[a * 4 + 3], sy);
  float wsA = __fadd_rn(__fsub_rn(ax2, ax1), 1.0f);
  float hsA = __fadd_rn(__fsub_rn(ay2, ay1), 1.0f);
  float cx = __fadd_rn(ax1, __fmul_rn(0.5f, wsA));
  float cy = __fadd_rn(ay1, __fmul_rn(0.5f, hsA));
  const float* dp = bbox + ((size_t)b * (4 * AN) + 4 * a) * HW + (size_t)h * WW + w;
  float dx = dp[0], dy = dp[HW], dwv = dp[2 * HW], dhv = dp[3 * HW];
  dwv = fminf(dwv, BCLIP);
  dhv = fminf(dhv, BCLIP);
  float pcx = __fadd_rn(__fmul_rn(dx, wsA), cx);
  float pcy = __fadd_rn(__fmul_rn(dy, hsA), cy);
  float pw = __fmul_rn((float)exp((double)dwv), wsA);
  float ph = __fmul_rn((float)exp((double)dhv), hsA);
  float hpw = __fmul_rn(0.5f, pw), hph = __fmul_rn(0.5f, ph);
  float x1 = __fsub_rn(pcx, hpw);
  float y1 = __fsub_rn(pcy, hph);
  float x2 = __fsub_rn(__fadd_rn(pcx, hpw), 1.0f);
  float y2 = __fsub_rn(__fadd_rn(pcy, hph), 1.0f);
  x1 = fminf(fmaxf(x1, 0.0f), wmax);
  y1 = fminf(fmaxf(y1, 0.0f), hmax);
  x2 = fminf(fmaxf(x2, 0.0f), wmax);
  y2 = fminf(fmaxf(y2, 0.0f), hmax);
  float ws2 = __fadd_rn(__fsub_rn(x2, x1), 1.0f);
  float hs2 = __fadd_rn(__fsub_rn(y2, y1), 1.0f);
  int v = (ws2 >= msz) && (hs2 >= msz) &&
          (__fadd_rn(x1, __fmul_rn(ws2, 0.5f)) < im_w) &&
          (__fadd_rn(y1, __fmul_rn(hs2, 0.5f)) < im_h);
  boxes[b * RSTRIDE + q] = make_float4(x1, y1, x2, y2);
  scores[b * RSTRIDE + q] = sc;
  valid[b * RSTRIDE + q] = v;
}

// triangular grid: 528 = 32*33/2 blocks per image
__global__ __launch_bounds__(64) void nms_mask_kernel(const float4* __restrict__ boxes,
                                                      u64* __restrict__ mask,
                                                      u64* __restrict__ diag) {
  int L = blockIdx.x, b = blockIdx.y;
  int ib = 0, rowlen = 32;
  while (L >= rowlen) { L -= rowlen; rowlen--; ib++; }
  int jb = ib + L;
  int t = threadIdx.x;
  __shared__ float4 jbox[64];
  __shared__ float jarea[64];
  int jbase = jb * 64;
  int jcount = min(64, PRE - jbase);
  if (t < jcount) {
    float4 bj = boxes[b * RSTRIDE + jbase + t];
    jbox[t] = bj;
    jarea[t] = areaf(bj);
  }
  __syncthreads();
  int i = ib * 64 + t;
  if (i >= PRE) return;
  float4 bi = boxes[b * RSTRIDE + i];
  float ai = areaf(bi);
  u64 word = 0ULL;
  for (int jj = 0; jj < jcount; ++jj) {
    int j = jbase + jj;
    if (j <= i) continue;
    float4 bj = jbox[jj];
    float iw = fmaxf(__fadd_rn(__fsub_rn(fminf(bi.z, bj.z), fmaxf(bi.x, bj.x)), 1.0f), 0.0f);
    float ih = fmaxf(__fadd_rn(__fsub_rn(fminf(bi.w, bj.w), fmaxf(bi.y, bj.y)), 1.0f), 0.0f);
    float inter = __fmul_rn(iw, ih);
    float denom = __fsub_rn(__fadd_rn(ai, jarea[jj]), inter);
    float iou = inter / denom;
    if (iou > 0.7f) word |= (1ULL << jj);
  }
  mask[((size_t)(b * RSTRIDE) + i) * ROWW + jb] = word;
  if (jb == ib) diag[(size_t)b * RSTRIDE + i] = word;   // packed diagonal word
}

// ---------------- seq NMS v13: sparse closure + parallel vbuf prologue ---
__global__ __launch_bounds__(512) void seq_nms_kernel(
    const u64* __restrict__ mask, const u64* __restrict__ diag,
    const int* __restrict__ valid,
    const float4* __restrict__ boxes, const float* __restrict__ scores,
    float* __restrict__ out) {
  int b = blockIdx.x;
  int tid = threadIdx.x;
  int wid = tid >> 6, lane = tid & 63, lw = lane & 31, hf = lane >> 5;
  __shared__ u64 partial[16];
  __shared__ u64 keepbLDS;
  __shared__ u64 vbufLDS[NCHUNK];
  __shared__ u64 kbits_s[NCHUNK];
  __shared__ int chunkoff[NCHUNK];
  __shared__ int keeplist[PRE];
  __shared__ int Ksh;
  __shared__ int stopSh;

  if (tid < 16) partial[tid] = 0ULL;
  if (tid < NCHUNK) kbits_s[tid] = 0ULL;
  if (tid == 0) stopSh = 0;
  // vbuf: all 8 waves in parallel, 4 chunks each
  for (int c = wid * 4; c < wid * 4 + 4; ++c) {
    int q = c * 64 + lane;
    int v = (q < PRE) ? valid[b * RSTRIDE + q] : 0;
    u64 bl = __ballot(v != 0);
    if (lane == 0) vbufLDS[c] = bl;
  }
  __syncthreads();

  const u64* base = mask + (size_t)b * RSTRIDE * ROWW;
  const u64* dg = diag + (size_t)b * RSTRIDE;

  u64 rem = 0ULL;
  u64 Dv = 0ULL;
  if (wid == 0) Dv = dg[lane];   // chunk 0 diag
  int rb0 = wid * 8 + hf;        // this lane's rows: rb0, rb0+2, rb0+4, rb0+6
  int tot = 0;
  u64 cur0 = base[(size_t)(rb0 + 0) * ROWW + lw];
  u64 cur1 = base[(size_t)(rb0 + 2) * ROWW + lw];
  u64 cur2 = base[(size_t)(rb0 + 4) * ROWW + lw];
  u64 cur3 = base[(size_t)(rb0 + 6) * ROWW + lw];
  for (int c = 0; c < NCHUNK; ++c) {
    u64 n0 = 0, n1 = 0, n2 = 0, n3 = 0, Dnext = 0ULL;
    if (c + 1 < NCHUNK) {
      int c0n = (c + 1) * 64;
      n0 = base[(size_t)(c0n + rb0 + 0) * ROWW + lw];
      n1 = base[(size_t)(c0n + rb0 + 2) * ROWW + lw];
      n2 = base[(size_t)(c0n + rb0 + 4) * ROWW + lw];
      n3 = base[(size_t)(c0n + rb0 + 6) * ROWW + lw];
      if (wid == 0) Dnext = dg[(size_t)(c + 1) * 64 + lane];
    }
    if (wid == 0) {
      u64 nz = __ballot(Dv != 0ULL);
      u64 cv = partial[0];
#pragma unroll
      for (int s = 1; s < 16; ++s) cv |= partial[s];
      u32 clo = (u32)__builtin_amdgcn_readfirstlane((int)(u32)cv);
      u32 chi = (u32)__builtin_amdgcn_readfirstlane((int)(u32)(cv >> 32));
      u64 cl = ((u64)chi << 32) | clo;
      u64 vbv = vbufLDS[c];
      u32 vlo = (u32)__builtin_amdgcn_readfirstlane((int)(u32)vbv);
      u32 vhi = (u32)__builtin_amdgcn_readfirstlane((int)(u32)(vbv >> 32));
      u64 vb = ((u64)vhi << 32) | vlo;
      // sparse serial closure (D[ii]==0 iterations are no-ops)
      u32 dloA = (u32)Dv, dhiA = (u32)(Dv >> 32);
      u64 work = nz & vb;
      while (work) {
        int ii = __builtin_ctzll(work);
        work &= work - 1ULL;
        u32 dlo = (u32)__builtin_amdgcn_readlane((int)dloA, ii);
        u32 dhi = (u32)__builtin_amdgcn_readlane((int)dhiA, ii);
        u64 D = ((u64)dhi << 32) | dlo;
        u64 tt = ((~cl & vb) >> ii) & 1ULL;
        cl |= tt ? D : 0ULL;
      }
      u64 keepb = vb & ~cl;
      tot += (int)__popcll(keepb);
      if (lane == 0) {
        keepbLDS = keepb;
        kbits_s[c] = keepb;
        if (tot >= POST) stopSh = 1;
      }
    }
    BAR_LGKM();                           // barrier 1 (vmcnt NOT drained)
    u64 keepb = keepbLDS;
    int stop = stopSh;
    rem |= cur0 & (0ULL - ((keepb >> (rb0 + 0)) & 1ULL));
    rem |= cur1 & (0ULL - ((keepb >> (rb0 + 2)) & 1ULL));
    rem |= cur2 & (0ULL - ((keepb >> (rb0 + 4)) & 1ULL));
    rem |= cur3 & (0ULL - ((keepb >> (rb0 + 6)) & 1ULL));
    int nw = (c + 1) & 31;
    if (lw == nw) partial[wid * 2 + hf] = rem;
    if (stop) break;
    BAR_LGKM();                           // barrier 2
    cur0 = n0; cur1 = n1; cur2 = n2; cur3 = n3;
    Dv = Dnext;
  }
  __syncthreads();

  // compact keep list
  if (wid == 0) {
    int pc = (lane < NCHUNK) ? (int)__popcll(kbits_s[lane]) : 0;
    int inc = pc;
    for (int d = 1; d < 64; d <<= 1) {
      int n = __shfl_up(inc, d, 64);
      if (lane >= d) inc += n;
    }
    if (lane < NCHUNK) chunkoff[lane] = inc - pc;
    if (lane == NCHUNK - 1) Ksh = inc;
  }
  __syncthreads();
  for (int c = wid * 4; c < wid * 4 + 4; ++c) {
    u64 word = kbits_s[c];
    if ((word >> lane) & 1ULL) {
      int rank = (int)__popcll(word & ((1ULL << lane) - 1ULL));
      keeplist[chunkoff[c] + rank] = c * 64 + lane;
    }
  }
  __syncthreads();
  int K = Ksh;

  float* rois = out;
  float* probs = out + (size_t)BN * POST * 5;
  for (int r = tid; r < POST; r += 512) {
    float x1 = 0.f, y1 = 0.f, x2 = 0.f, y2 = 0.f, pr = 0.f;
    if (r < K) {
      int i = keeplist[r];
      float4 bb = boxes[b * RSTRIDE + i];
      x1 = bb.x; y1 = bb.y; x2 = bb.z; y2 = bb.w;
      pr = scores[b * RSTRIDE + i];
    }
    size_t ro = (size_t)(b * POST + r) * 5;
    rois[ro + 0] = (float)b;
    rois[ro + 1] = x1; rois[ro + 2] = y1; rois[ro + 3] = x2; rois[ro + 4] = y2;
    probs[b * POST + r] = pr;
  }
}

extern "C" void kernel_launch(void* const* d_in, const int* in_sizes, int n_in,
                              void* d_out, int out_size, void* d_ws, size_t ws_size,
                              hipStream_t stream) {
  const float* cls    = (const float*)d_in[0];
  const float* bbox   = (const float*)d_in[1];
  const float* iminfo = (const float*)d_in[2];
  const float* anch   = (const float*)d_in[3];
  char* ws = (char*)d_ws;
  u32* h1    = (u32*)(ws + OFF_H1);
  u32* h2    = (u32*)(ws + OFF_H2);
  u32* cstar = (u32*)(ws + OFF_CSTAR);
  u32* ccnt  = (u32*)(ws + OFF_CCNT);
  u32* thr   = (u32*)(ws + OFF_THR);
  u64* cand  = (u64*)(ws + OFF_CAND);
  float4* boxes = (float4*)(ws + OFF_BOX);
  float* scores = (float*)(ws + OFF_SCORE);
  int* valid    = (int*)(ws + OFF_VALID);
  u64* mask     = (u64*)(ws + OFF_MASK);
  u64* diag     = (u64*)(ws + OFF_DIAG);
  u64* skeys    = (u64*)(ws + OFF_SKEYS);
  float* out = (float*)d_out;

  hist1_kernel<<<dim3(HBLK, BN), 256, 0, stream>>>(cls, h1);
  hist2_kernel<<<dim3(HBLK, BN), 256, 0, stream>>>(cls, h1, cstar, ccnt, h2);
  gather_kernel<<<dim3(GBLK, BN), 256, 0, stream>>>(cls, h2, cstar, thr, ccnt, cand);
  sort_kernel<<<BN, 1024, 0, stream>>>(cand, ccnt, thr, skeys);
  transform_kernel<<<dim3(8, BN), 256, 0, stream>>>(skeys, ccnt, bbox, iminfo, anch,
                                                    boxes, scores, valid);
  nms_mask_kernel<<<dim3(528, BN), 64, 0, stream>>>(boxes, mask, diag);
  seq_nms_kernel<<<BN, 512, 0, stream>>>(mask, diag, valid, boxes, scores, out);
}